// Round 6
// baseline (653.873 us; speedup 1.0000x reference)
//
#include <hip/hip_runtime.h>
#include <math.h>
#include <stdint.h>

typedef unsigned short u16;
typedef unsigned int u32;
typedef float floatx4 __attribute__((ext_vector_type(4)));
typedef __bf16 bf16x8 __attribute__((ext_vector_type(8)));

#define T_TOK 3152      // B*L = 16*197
#define SEQ 197
#define NH 12
#define LISTN 8448      // 33 tiles * 256 (worst-case 256-aligned expert segments)
#define MOE1_MT 33      // 256-row tiles
#define MOE2_MT 66      // 128-row tiles

__device__ __forceinline__ float bf2f(u16 u) { return __uint_as_float(((u32)u) << 16); }
__device__ __forceinline__ u16 f2bf(float f) {
    u32 u = __float_as_uint(f);
    u += 0x7FFFu + ((u >> 16) & 1u);   // RNE
    return (u16)(u >> 16);
}
__device__ __forceinline__ float wred_sum(float v) {
#pragma unroll
    for (int off = 32; off; off >>= 1) v += __shfl_xor(v, off);
    return v;
}

// fast exact-enough gelu: A&S 7.1.26 erf, |err| <= 1.5e-7 (abs) -> bf16-identical vs erff
__device__ __forceinline__ float gelu_fast(float v) {
    float x = fabsf(v) * 0.70710678118654752f;
    float t = __builtin_amdgcn_rcpf(fmaf(0.3275911f, x, 1.0f));
    float p = t * fmaf(t, fmaf(t, fmaf(t, fmaf(t, 1.061405429f, -1.453152027f),
                                       1.421413741f), -0.284496736f), 0.254829592f);
    float er = fmaf(-p, __expf(-x * x), 1.0f);   // erf(|x|)
    er = copysignf(er, v);
    return 0.5f * v * (1.0f + er);
}

// async global->LDS, 16B per lane; LDS dest must be wave-uniform base (+lane*16 implicit)
#define GLB_AS(p) ((const __attribute__((address_space(1))) void*)(uintptr_t)(p))
#define LDS_AS(p) ((__attribute__((address_space(3))) void*)(uintptr_t)(p))
__device__ __forceinline__ void gl_lds16(const u16* g, u16* l) {
    __builtin_amdgcn_global_load_lds(GLB_AS(g), LDS_AS(l), 16, 0, 0);
}

// ---------------- weight prep: in f32 [z][R][C] -> out bf16 [z][C][R] (opt split hi/lo) ----------------
template <int SPLIT>
__global__ __launch_bounds__(256) void transp_kernel(const float* __restrict__ in,
        u16* __restrict__ oh, u16* __restrict__ ol, int R, int C) {
    int r0 = blockIdx.x * 64, c0 = blockIdx.y * 64;
    size_t zo = (size_t)blockIdx.z * R * C;
    __shared__ float Lt[64][68];
    int tid = threadIdx.x;
    int rr = tid >> 2, cs = (tid & 3) * 16;
    const float* src = in + zo + (size_t)(r0 + rr) * C + c0 + cs;
#pragma unroll
    for (int i = 0; i < 4; i++) *(float4*)&Lt[rr][cs + i * 4] = *(const float4*)(src + i * 4);
    __syncthreads();
    int cw = tid >> 2, rs = (tid & 3) * 16;
    u16 hv[16], lv[16];
#pragma unroll
    for (int j = 0; j < 16; j++) {
        float v = Lt[rs + j][cw];
        u16 hb = f2bf(v);
        hv[j] = hb;
        if (SPLIT) lv[j] = f2bf(v - bf2f(hb));
    }
    u16* dst = oh + zo + (size_t)(c0 + cw) * R + r0 + rs;
    *(uint4*)dst = *(const uint4*)&hv[0];
    *(uint4*)(dst + 8) = *(const uint4*)&hv[8];
    if (SPLIT) {
        u16* dstl = ol + zo + (size_t)(c0 + cw) * R + r0 + rs;
        *(uint4*)dstl = *(const uint4*)&lv[0];
        *(uint4*)(dstl + 8) = *(const uint4*)&lv[8];
    }
}

// ---------------- LN1: h = LN(x)*g+b, split to bf16 hi/lo planes ----------------
__global__ __launch_bounds__(256) void ln1_kernel(const float* __restrict__ x,
        const float* __restrict__ g, const float* __restrict__ b,
        u16* __restrict__ h_hi, u16* __restrict__ h_lo) {
    int t = blockIdx.x, tid = threadIdx.x;
    int w = tid >> 6, lane = tid & 63;
    float v[3];
#pragma unroll
    for (int i = 0; i < 3; i++) v[i] = x[(size_t)t * 768 + tid + i * 256];
    float s = v[0] + v[1] + v[2];
    float q = v[0] * v[0] + v[1] * v[1] + v[2] * v[2];
    s = wred_sum(s); q = wred_sum(q);
    __shared__ float red[8];
    if (lane == 0) { red[w] = s; red[4 + w] = q; }
    __syncthreads();
    float st = red[0] + red[1] + red[2] + red[3];
    float qt = red[4] + red[5] + red[6] + red[7];
    float mean = st * (1.f / 768.f);
    float var = qt * (1.f / 768.f) - mean * mean;
    float rs = rsqrtf(var + 1e-5f);
#pragma unroll
    for (int i = 0; i < 3; i++) {
        int d = tid + i * 256;
        float hv = (v[i] - mean) * rs * g[d] + b[d];
        u16 hi = f2bf(hv);
        h_hi[(size_t)t * 768 + d] = hi;
        h_lo[(size_t)t * 768 + d] = f2bf(hv - bf2f(hi));
    }
}

// ---------------- 128x128 MFMA GEMM (modes 0/1/3) ----------------
// global_load_lds staging. SPLIT modes (0/1): double-buffer + drain (48 MFMA/step covers latency).
// MODE 3: TRIPLE-buffer counted-vmcnt pipeline (r4-proven 48KB config).
// XCD-partitioned bijective grid swizzle. B pre-transposed bf16 [n][k].
// MODE 0: qkv split -> bf16 hi/lo planes (Cv/Cv2). MODE 1: proj split + resid -> f32.
// MODE 3: moe2 dense A -> f32, split-K; z=0 -> Cv, z=1 -> Cv2 (separate buffers).
template <int MODE>
__global__ __launch_bounds__(256) void gemm128(const u16* __restrict__ Ah,
        const u16* __restrict__ Al, const u16* __restrict__ Bh, const u16* __restrict__ Bl,
        const float* __restrict__ bias, void* __restrict__ Cv, void* __restrict__ Cv2,
        const float* __restrict__ resid,
        const int* __restrict__ list, const int* __restrict__ asg, int M, int N, int K) {
    constexpr bool SPLIT = (MODE <= 1);
    constexpr int GX = (MODE <= 1) ? 25 : MOE2_MT;                   // m-tiles
    constexpr int GY = (MODE == 0) ? 18 : 6;                         // n-tiles
    constexpr int GZ = (MODE == 3) ? 2 : 1;                          // split-K
    constexpr int G  = GX * GY * GZ;
    constexpr int NT = GY * GZ;
    constexpr int Q8 = G >> 3, R8 = G & 7;

    // dispatch index -> XCD-contiguous tile id (bijective, m204 form); HW round-robins d%8 over XCDs
    int d = blockIdx.x + GX * (blockIdx.y + GY * blockIdx.z);
    int j = d & 7, s = d >> 3;
    int v = (j < R8) ? (j * (Q8 + 1) + s) : (R8 * (Q8 + 1) + (j - R8) * Q8 + s);
    int mt = v / NT, nzr = v - mt * NT;
    int yt = nzr % GY, zt = nzr / GY;
    int m0 = mt * 128, n0 = yt * 128;

    const u16* Bph = Bh;
    const float* bp = bias;
    const u16* Bpl = Bl;
    if (MODE == 3) {
        if (m0 >= asg[8]) return;
        int e = 0;
        while (m0 >= asg[e + 1]) ++e;    // uniform across block
        Bph = Bh + (size_t)e * N * K;
        bp = bias + (size_t)e * N;
    }
    int kbeg = 0, kend = K;
    if (MODE == 3) { int kh = K >> 1; kbeg = zt * kh; kend = kbeg + kh; }

    // LDS pool. SPLIT: 2 bufs x {Ah,Bh,Al,Bl} x 8KB = 64KB. MODE3: 3 bufs x {A,B} x 8KB = 48KB.
    __shared__ __align__(16) u16 SM[SPLIT ? 32768 : 24576];
    u16* Ash = SM;
    u16* Bsh = SM + (SPLIT ? 8192 : 12288);
    u16* Asl = SM + 16384;   // SPLIT only
    u16* Bsl = SM + 24576;   // SPLIT only

    int tid = threadIdx.x;
    int w = tid >> 6, lane = tid & 63, l15 = lane & 15, quad = lane >> 4;
    int wm = (w & 1) * 64, wn = (w >> 1) * 64;
    int lr = lane >> 2;
    // source granule swizzle: LDS slot (row=lane>>2, gpos=lane&3) holds logical granule
    // gpos ^ ((row>>1)&3); since (lane>>3)&3 == (tile_row>>1)&3 this is per-lane source math only.
    int lc = ((lane & 3) ^ ((lane >> 3) & 3)) * 8;

    const u16* ga[2]; const u16* gal[2];
    const u16* gb[2]; const u16* gbl[2];
    int ldro[2];
#pragma unroll
    for (int it = 0; it < 2; it++) {
        int arow = m0 + it * 64 + w * 16 + lr;
        if (MODE == 3) {
            ga[it] = Ah + (size_t)arow * K + lc;   // padding rows finite poison; store-guarded
        } else {
            int rc = min(arow, M - 1);
            ga[it] = Ah + (size_t)rc * K + lc;
            gal[it] = Al + (size_t)rc * K + lc;
        }
        int brow = n0 + it * 64 + w * 16 + lr;
        gb[it] = Bph + (size_t)brow * K + lc;
        if (SPLIT) gbl[it] = Bpl + (size_t)brow * K + lc;
        ldro[it] = (it * 64 + w * 16) * 32;       // wave-uniform LDS chunk base (within a buffer)
    }

    // read addresses (loop-invariant): row-major [128][32] with XOR granule de-swizzle
    int ra[4], rb[4];
#pragma unroll
    for (int i = 0; i < 4; i++) {
        int r1 = wm + i * 16 + l15;
        ra[i] = r1 * 32 + (quad ^ ((r1 >> 1) & 3)) * 8;
        int r2 = wn + i * 16 + l15;
        rb[i] = r2 * 32 + (quad ^ ((r2 >> 1) & 3)) * 8;
    }

    floatx4 acc[4][4];
#pragma unroll
    for (int mi = 0; mi < 4; mi++)
#pragma unroll
        for (int ni = 0; ni < 4; ni++) acc[mi][ni] = (floatx4){0.f, 0.f, 0.f, 0.f};

    auto stage = [&](int buf, int k0) {
        int bo = buf * 4096;
#pragma unroll
        for (int it = 0; it < 2; it++) {
            gl_lds16(ga[it] + k0, &Ash[bo + ldro[it]]);
            gl_lds16(gb[it] + k0, &Bsh[bo + ldro[it]]);
            if constexpr (SPLIT) {
                gl_lds16(gal[it] + k0, &Asl[bo + ldro[it]]);
                gl_lds16(gbl[it] + k0, &Bsl[bo + ldro[it]]);
            }
        }
    };
    auto compute = [&](int buf) {
        int bo = buf * 4096;
        bf16x8 afh[4], bfh[4], afl[4], bfl[4];
#pragma unroll
        for (int i = 0; i < 4; i++) {
            afh[i] = *(const bf16x8*)&Ash[bo + ra[i]];
            bfh[i] = *(const bf16x8*)&Bsh[bo + rb[i]];
            if constexpr (SPLIT) {
                afl[i] = *(const bf16x8*)&Asl[bo + ra[i]];
                bfl[i] = *(const bf16x8*)&Bsl[bo + rb[i]];
            }
        }
        if constexpr (!SPLIT) __builtin_amdgcn_s_setprio(1);
#pragma unroll
        for (int mi = 0; mi < 4; mi++)
#pragma unroll
            for (int ni = 0; ni < 4; ni++) {
                if constexpr (SPLIT) {
                    acc[mi][ni] = __builtin_amdgcn_mfma_f32_16x16x32_bf16(afl[mi], bfh[ni], acc[mi][ni], 0, 0, 0);
                    acc[mi][ni] = __builtin_amdgcn_mfma_f32_16x16x32_bf16(afh[mi], bfl[ni], acc[mi][ni], 0, 0, 0);
                }
                acc[mi][ni] = __builtin_amdgcn_mfma_f32_16x16x32_bf16(afh[mi], bfh[ni], acc[mi][ni], 0, 0, 0);
            }
        if constexpr (!SPLIT) __builtin_amdgcn_s_setprio(0);
    };

    int nsteps = (kend - kbeg) >> 5;
    if constexpr (SPLIT) {
        stage(0, kbeg);
        __syncthreads();
        for (int s2 = 0; s2 < nsteps; s2 += 2) {
            int k0 = kbeg + s2 * 32;
            stage(1, k0 + 32);
            compute(0);
            __syncthreads();
            if (s2 + 2 < nsteps) stage(0, k0 + 64);
            compute(1);
            __syncthreads();
        }
    } else {
        // depth-3 counted-vmcnt pipeline (r4-proven); 4 gl_lds per stage per wave.
        stage(0, kbeg);
        stage(1, kbeg + 32);
        asm volatile("s_waitcnt vmcnt(4)" ::: "memory");   // buf0 landed (buf1 = 4 in flight)
        __builtin_amdgcn_s_barrier();
        int bufc = 0;
        for (int t = 0; t < nsteps; ++t) {
            int b2 = bufc + 2; if (b2 >= 3) b2 -= 3;
            if (t + 2 < nsteps) stage(b2, kbeg + (t + 2) * 32);   // overwrites buf(t-1): freed by prev barrier
            compute(bufc);
            if (t + 2 < nsteps) {
                asm volatile("s_waitcnt vmcnt(4) lgkmcnt(0)" ::: "memory");
            } else {
                asm volatile("s_waitcnt vmcnt(0) lgkmcnt(0)" ::: "memory");
            }
            __builtin_amdgcn_s_barrier();
            bufc = (bufc == 2) ? 0 : bufc + 1;
        }
    }

    float* Cf = (float*)Cv;
    if (MODE == 3 && zt != 0) Cf = (float*)Cv2;
#pragma unroll
    for (int ni = 0; ni < 4; ni++) {
        int col = n0 + wn + ni * 16 + l15;
        float bb = bp[col];
        if (MODE == 3 && zt != 0) bb = 0.f;   // bias added once (z=0 half)
#pragma unroll
        for (int mi = 0; mi < 4; mi++) {
#pragma unroll
            for (int r = 0; r < 4; r++) {
                int row = m0 + wm + mi * 16 + quad * 4 + r;
                float v2 = acc[mi][ni][r] + bb;
                if (MODE == 0) {
                    if (row < M) {
                        u16 hb = f2bf(v2);
                        ((u16*)Cv)[(size_t)row * N + col] = hb;
                        ((u16*)Cv2)[(size_t)row * N + col] = f2bf(v2 - bf2f(hb));
                    }
                } else if (MODE == 1) {
                    if (row < M) Cf[(size_t)row * N + col] = v2 + resid[(size_t)row * N + col];
                } else {
                    if (list[row] >= 0) Cf[(size_t)row * N + col] = v2;
                }
            }
        }
    }
}

// ---------------- moe1: 256x256 tile, 8 waves, dbuf counted-vmcnt; gathered A; gelu -> bf16 ----------------
// Halves L3 traffic vs 128x128 (panel re-reads scale with tile count). Expert segments 256-aligned.
__global__ __launch_bounds__(512, 1) void gemm256_moe1(const u16* __restrict__ Ah,
        const u16* __restrict__ Bh, const float* __restrict__ bias, u16* __restrict__ Cv,
        const int* __restrict__ list, const int* __restrict__ asg) {
    constexpr int GX = MOE1_MT, GY = 12, G = GX * GY;   // 396
    constexpr int Q8 = G >> 3, R8 = G & 7;
    constexpr int N = 3072, K = 768, NSTEP = 24;

    int d = blockIdx.x + GX * blockIdx.y;
    int j = d & 7, s = d >> 3;
    int v = (j < R8) ? (j * (Q8 + 1) + s) : (R8 * (Q8 + 1) + (j - R8) * Q8 + s);
    int mt = v / GY, yt = v - mt * GY;
    int m0 = mt * 256, n0 = yt * 256;
    if (m0 >= asg[8]) return;
    int e = 0;
    while (m0 >= asg[e + 1]) ++e;       // 256-aligned segments: uniform expert per block
    const u16* Bph = Bh + (size_t)e * N * K;
    const float* bp = bias + (size_t)e * N;

    __shared__ __align__(16) u16 SM[32768];   // A[2][8192] @0, B[2][8192] @16384; epilogue: [128][256] bf16

    int tid = threadIdx.x;
    int w = tid >> 6, lane = tid & 63, l15 = lane & 15, quad = lane >> 4;
    int wr = w >> 2, wc = w & 3;              // wave tile: rows wr*128, cols wc*64
    int lc = ((lane & 3) ^ ((lane >> 3) & 3)) * 8;   // source granule swizzle

    int ar0 = m0 + (tid >> 2);
    int le0 = list[ar0], le1 = list[ar0 + 128];
    const u16* gA0 = Ah + (size_t)(le0 >= 0 ? (le0 >> 1) : 0) * K + lc;
    const u16* gA1 = Ah + (size_t)(le1 >= 0 ? (le1 >> 1) : 0) * K + lc;
    const u16* gB0 = Bph + (size_t)(n0 + (tid >> 2)) * K + lc;
    const u16* gB1 = Bph + (size_t)(n0 + 128 + (tid >> 2)) * K + lc;
    int chunk = w * 512;                      // wave-uniform LDS chunk (16 rows x 32 u16)

    int ra[8], rb[4];
#pragma unroll
    for (int i = 0; i < 8; i++) { int r = wr * 128 + i * 16 + l15; ra[i] = r * 32 + (quad ^ ((r >> 1) & 3)) * 8; }
#pragma unroll
    for (int i = 0; i < 4; i++) { int r = wc * 64 + i * 16 + l15; rb[i] = r * 32 + (quad ^ ((r >> 1) & 3)) * 8; }

    floatx4 acc[8][4];
#pragma unroll
    for (int i = 0; i < 8; i++)
#pragma unroll
        for (int j2 = 0; j2 < 4; j2++) acc[i][j2] = (floatx4){0.f, 0.f, 0.f, 0.f};

    auto stage = [&](int buf, int k0) {
        u16* la = &SM[buf * 8192];
        u16* lb = &SM[16384 + buf * 8192];
        gl_lds16(gA0 + k0, la + chunk);
        gl_lds16(gA1 + k0, la + 4096 + chunk);
        gl_lds16(gB0 + k0, lb + chunk);
        gl_lds16(gB1 + k0, lb + 4096 + chunk);
    };
    auto compute = [&](int buf) {
        const u16* la = &SM[buf * 8192];
        const u16* lb = &SM[16384 + buf * 8192];
        bf16x8 af[8], bf[4];
#pragma unroll
        for (int i = 0; i < 8; i++) af[i] = *(const bf16x8*)&la[ra[i]];
#pragma unroll
        for (int i = 0; i < 4; i++) bf[i] = *(const bf16x8*)&lb[rb[i]];
        __builtin_amdgcn_s_setprio(1);
#pragma unroll
        for (int i = 0; i < 8; i++)
#pragma unroll
            for (int j2 = 0; j2 < 4; j2++)
                acc[i][j2] = __builtin_amdgcn_mfma_f32_16x16x32_bf16(af[i], bf[j2], acc[i][j2], 0, 0, 0);
        __builtin_amdgcn_s_setprio(0);
    };

    stage(0, 0);
    for (int t = 0; t < NSTEP; ++t) {
        if (t + 1 < NSTEP) {
            stage((t + 1) & 1, (t + 1) * 32);
            asm volatile("s_waitcnt vmcnt(4)" ::: "memory");   // buf t landed; t+1 in flight
        } else {
            asm volatile("s_waitcnt vmcnt(0)" ::: "memory");
        }
        __builtin_amdgcn_s_barrier();
        compute(t & 1);
        __builtin_amdgcn_s_barrier();   // all waves done reading buf t before it's restaged
    }

    // epilogue: two 128-row phases through LDS for coalesced bf16 stores
#pragma unroll
    for (int p = 0; p < 2; p++) {
        if (wr == p) {
#pragma unroll
            for (int j2 = 0; j2 < 4; j2++) {
                int col = wc * 64 + j2 * 16 + l15;
                float bb = bp[n0 + col];
#pragma unroll
                for (int i = 0; i < 8; i++) {
#pragma unroll
                    for (int r = 0; r < 4; r++) {
                        int row = i * 16 + quad * 4 + r;
                        SM[row * 256 + (col ^ ((row & 7) << 3))] = f2bf(gelu_fast(acc[i][j2][r] + bb));
                    }
                }
            }
        }
        __syncthreads();
        int row = tid >> 2, cb0 = (tid & 3) * 64;
        int grow = m0 + p * 128 + row;
        if (list[grow] >= 0) {
            u16* dst = Cv + (size_t)grow * N + n0 + cb0;
            int xr = (row & 7) << 3;
#pragma unroll
            for (int ch = 0; ch < 8; ch++) {
                int cc = (cb0 + ch * 8) ^ xr;
                *(uint4*)(dst + ch * 8) = *(const uint4*)&SM[row * 256 + cc];
            }
        }
        __syncthreads();
    }
}

// ---------------- MFMA attention: bf16 hi/lo qkv planes; block = (b, h, 64-q-tile), 4 waves ----------------
__global__ __launch_bounds__(256) void attn_mfma_kernel(const u16* __restrict__ qph,
        const u16* __restrict__ qpl, u16* __restrict__ ohi, u16* __restrict__ olo) {
    // bijective XCD swizzle over 768 blocks: XCD j gets 24 consecutive (b,h) with all 4 q-tiles
    int d = blockIdx.x + 4 * blockIdx.y;
    int j = d & 7, sdx = d >> 3;
    int v = j * 96 + sdx;
    int qbase = (v & 3) * 64;
    int by = v >> 2;
    int b = by / NH, h = by % NH;
    int tid = threadIdx.x;
    int w = tid >> 6, lane = tid & 63, l15 = lane & 15, quad = lane >> 4;

    __shared__ u16 Qh[64 * 64], Ql[64 * 64];
    __shared__ u16 Sh[64 * 64], Sl[64 * 64];   // K tile, then V^T tile
    __shared__ u16 Ph[64 * 72], Pl[64 * 72];

    int grow8 = lane >> 3;                     // row within 8-row gl_lds group
    int gsrc = ((lane & 7) ^ grow8) * 8;       // swizzled source granule (u16 offset)
    int srow = tid >> 2;                       // V^T: key index
    int scol = (tid & 3) * 16;                 // V^T: d base

    // --- stage Q (gl_lds, swizzled) ---
#pragma unroll
    for (int it = 0; it < 2; it++) {
        int r = qbase + w * 16 + it * 8 + grow8;
        int rc = min(r, SEQ - 1);
        size_t so = (size_t)(b * SEQ + rc) * 2304 + h * 64 + gsrc;
        gl_lds16(qph + so, &Qh[(w * 16 + it * 8) * 64]);
        gl_lds16(qpl + so, &Ql[(w * 16 + it * 8) * 64]);
    }
    __syncthreads();
    bf16x8 aqh[2], aql[2];
#pragma unroll
    for (int s2 = 0; s2 < 2; s2++) {
        int row = w * 16 + l15;
        int ad = row * 64 + (((s2 * 4 + quad) ^ (row & 7))) * 8;
        aqh[s2] = *(const bf16x8*)&Qh[ad];
        aql[s2] = *(const bf16x8*)&Ql[ad];
    }

    floatx4 sc[16];
#pragma unroll
    for (int f = 0; f < 16; f++) sc[f] = (floatx4){0.f, 0.f, 0.f, 0.f};

    for (int t = 0; t < 4; t++) {
#pragma unroll
        for (int it = 0; it < 2; it++) {
            int r = t * 64 + w * 16 + it * 8 + grow8;
            int rc = min(r, SEQ - 1);
            size_t so = (size_t)(b * SEQ + rc) * 2304 + 768 + h * 64 + gsrc;
            gl_lds16(qph + so, &Sh[(w * 16 + it * 8) * 64]);
            gl_lds16(qpl + so, &Sl[(w * 16 + it * 8) * 64]);
        }
        __syncthreads();
#pragma unroll
        for (int s = 0; s < 4; s++) {
            int row = s * 16 + l15;
#pragma unroll
            for (int s2 = 0; s2 < 2; s2++) {
                int ad = row * 64 + (((s2 * 4 + quad) ^ (row & 7))) * 8;
                bf16x8 bkh = *(const bf16x8*)&Sh[ad];
                bf16x8 bkl = *(const bf16x8*)&Sl[ad];
                sc[t * 4 + s] = __builtin_amdgcn_mfma_f32_16x16x32_bf16(aql[s2], bkh, sc[t * 4 + s], 0, 0, 0);
                sc[t * 4 + s] = __builtin_amdgcn_mfma_f32_16x16x32_bf16(aqh[s2], bkl, sc[t * 4 + s], 0, 0, 0);
                sc[t * 4 + s] = __builtin_amdgcn_mfma_f32_16x16x32_bf16(aqh[s2], bkh, sc[t * 4 + s], 0, 0, 0);
            }
        }
        __syncthreads();
    }

    float m[4] = {-1e30f, -1e30f, -1e30f, -1e30f};
#pragma unroll
    for (int f = 0; f < 16; f++) {
        int key = (f >> 2) * 64 + (f & 3) * 16 + l15;
        bool valid = key < SEQ;
#pragma unroll
        for (int r = 0; r < 4; r++) {
            float s = valid ? sc[f][r] * 0.125f : -1e30f;
            sc[f][r] = s;
            m[r] = fmaxf(m[r], s);
        }
    }
#pragma unroll
    for (int r = 0; r < 4; r++) {
#pragma unroll
        for (int off = 1; off < 16; off <<= 1) m[r] = fmaxf(m[r], __shfl_xor(m[r], off));
    }
    float sum[4] = {0.f, 0.f, 0.f, 0.f};
#pragma unroll
    for (int f = 0; f < 16; f++) {
#pragma unroll
        for (int r = 0; r < 4; r++) {
            float p = expf(sc[f][r] - m[r]);
            sc[f][r] = p;
            sum[r] += p;
        }
    }
    float inv[4];
#pragma unroll
    for (int r = 0; r < 4; r++) {
#pragma unroll
        for (int off = 1; off < 16; off <<= 1) sum[r] += __shfl_xor(sum[r], off);
        inv[r] = 1.f / sum[r];
    }

    floatx4 oacc[4];
#pragma unroll
    for (int sd = 0; sd < 4; sd++) oacc[sd] = (floatx4){0.f, 0.f, 0.f, 0.f};

    for (int t = 0; t < 4; t++) {
#pragma unroll
        for (int s = 0; s < 4; s++) {
#pragma unroll
            for (int r = 0; r < 4; r++) {
                float p = sc[t * 4 + s][r];
                u16 hb = f2bf(p);
                int row = w * 16 + quad * 4 + r;
                Ph[row * 72 + s * 16 + l15] = hb;
                Pl[row * 72 + s * 16 + l15] = f2bf(p - bf2f(hb));
            }
        }
        {
            // V^T staging from bf16 planes (u16-only), granule-swizzled for conflict-free reads
            int key = t * 64 + srow;
            int kc = min(key, SEQ - 1);   // garbage rows hit P==0 (masked scores), finite => safe
            size_t so = (size_t)(b * SEQ + kc) * 2304 + 1536 + h * 64 + scol;
            u16 hv[16], lv[16];
            *(uint4*)&hv[0] = *(const uint4*)(qph + so);
            *(uint4*)&hv[8] = *(const uint4*)(qph + so + 8);
            *(uint4*)&lv[0] = *(const uint4*)(qpl + so);
            *(uint4*)&lv[8] = *(const uint4*)(qpl + so + 8);
            int kg = srow >> 3, kw = srow & 7;
#pragma unroll
            for (int i = 0; i < 16; i++) {
                int dcol = scol + i;
                int idx = dcol * 64 + ((kg ^ (dcol & 7)) * 8) + kw;
                Sh[idx] = hv[i];
                Sl[idx] = lv[i];
            }
        }
        __syncthreads();
#pragma unroll
        for (int s2 = 0; s2 < 2; s2++) {
            bf16x8 aph = *(const bf16x8*)&Ph[(w * 16 + l15) * 72 + s2 * 32 + quad * 8];
            bf16x8 apl = *(const bf16x8*)&Pl[(w * 16 + l15) * 72 + s2 * 32 + quad * 8];
#pragma unroll
            for (int sd = 0; sd < 4; sd++) {
                int row = sd * 16 + l15;
                int ad = row * 64 + (((s2 * 4 + quad) ^ (row & 7))) * 8;
                bf16x8 bvh = *(const bf16x8*)&Sh[ad];
                bf16x8 bvl = *(const bf16x8*)&Sl[ad];
                oacc[sd] = __builtin_amdgcn_mfma_f32_16x16x32_bf16(apl, bvh, oacc[sd], 0, 0, 0);
                oacc[sd] = __builtin_amdgcn_mfma_f32_16x16x32_bf16(aph, bvl, oacc[sd], 0, 0, 0);
                oacc[sd] = __builtin_amdgcn_mfma_f32_16x16x32_bf16(aph, bvh, oacc[sd], 0, 0, 0);
            }
        }
        __syncthreads();
    }

#pragma unroll
    for (int sd = 0; sd < 4; sd++) {
#pragma unroll
        for (int r = 0; r < 4; r++) {
            int q = qbase + w * 16 + quad * 4 + r;
            if (q < SEQ) {
                float val = oacc[sd][r] * inv[r];
                u16 hb = f2bf(val);
                size_t o = ((size_t)(b * SEQ + q)) * 768 + h * 64 + sd * 16 + l15;
                ohi[o] = hb;
                olo[o] = f2bf(val - bf2f(hb));
            }
        }
    }
}

// ---------------- LN2 + gate (top-2 of 8) ----------------
__global__ __launch_bounds__(256) void ln2_gate_kernel(const float* __restrict__ x1,
        const float* __restrict__ g, const float* __restrict__ b, const float* __restrict__ wg,
        u16* __restrict__ flat, int2* __restrict__ idx, float2* __restrict__ gate) {
    int t = blockIdx.x, tid = threadIdx.x;
    int w = tid >> 6, lane = tid & 63;
    float v[3];
#pragma unroll
    for (int i = 0; i < 3; i++) v[i] = x1[(size_t)t * 768 + tid + i * 256];
    float s = v[0] + v[1] + v[2];
    float q = v[0] * v[0] + v[1] * v[1] + v[2] * v[2];
    s = wred_sum(s); q = wred_sum(q);
    __shared__ float red[8];
    __shared__ float fs[768];
    __shared__ float lg[8];
    if (lane == 0) { red[w] = s; red[4 + w] = q; }
    __syncthreads();
    float st = red[0] + red[1] + red[2] + red[3];
    float qt = red[4] + red[5] + red[6] + red[7];
    float mean = st * (1.f / 768.f);
    float var = qt * (1.f / 768.f) - mean * mean;
    float rs = rsqrtf(var + 1e-5f);
#pragma unroll
    for (int i = 0; i < 3; i++) {
        int d = tid + i * 256;
        float f = (v[i] - mean) * rs * g[d] + b[d];
        flat[(size_t)t * 768 + d] = f2bf(f);
        fs[d] = f;
    }
    __syncthreads();
    int e0 = 2 * w, e1 = 2 * w + 1;
    float p0 = 0.f, p1 = 0.f;
    for (int d = lane; d < 768; d += 64) {
        float f = fs[d];
        p0 += f * wg[d * 8 + e0];
        p1 += f * wg[d * 8 + e1];
    }
    p0 = wred_sum(p0); p1 = wred_sum(p1);
    if (lane == 0) { lg[e0] = p0; lg[e1] = p1; }
    __syncthreads();
    if (tid == 0) {
        float b0 = -1e30f, b1 = -1e30f;
        int i0 = 0, i1 = 0;
        for (int e = 0; e < 8; e++) {     // strict > keeps first occurrence (jax tie-break)
            float le = lg[e];
            if (le > b0) { b1 = b0; i1 = i0; b0 = le; i0 = e; }
            else if (le > b1) { b1 = le; i1 = e; }
        }
        float ex = expf(b1 - b0);
        float den = 1.f + ex;
        idx[t] = make_int2(i0, i1);
        gate[t] = make_float2(1.f / den, ex / den);
    }
}

// ---------------- routing ----------------
__global__ __launch_bounds__(256) void hist_kernel(const int2* __restrict__ idx, int* __restrict__ cnt) {
    int t = blockIdx.x * 256 + threadIdx.x;
    if (t < T_TOK) {
        int2 id = idx[t];
        atomicAdd(&cnt[id.x], 1);
        atomicAdd(&cnt[id.y], 1);
    }
}

__global__ void offsets_kernel(const int* __restrict__ cnt, int* __restrict__ asg) {
    if (threadIdx.x == 0 && blockIdx.x == 0) {
        int acc = 0;
        asg[0] = 0;
        for (int e = 0; e < 8; e++) { acc += (cnt[e] + 255) & ~255; asg[e + 1] = acc; }
    }
}

__global__ __launch_bounds__(256) void scatter_kernel(const int2* __restrict__ idx,
        const int* __restrict__ asg, int* __restrict__ cursor,
        int* __restrict__ list, int* __restrict__ pos) {
    int t = blockIdx.x * 256 + threadIdx.x;
    if (t >= T_TOK) return;
    int2 id = idx[t];
    int p0 = asg[id.x] + atomicAdd(&cursor[id.x], 1);
    list[p0] = t * 2;
    pos[t * 2] = p0;
    int p1 = asg[id.y] + atomicAdd(&cursor[id.y], 1);
    list[p1] = t * 2 + 1;
    pos[t * 2 + 1] = p1;
}

// ---------------- final: out = x1 + g0*(y0[p0]+y1[p0]) + g1*(y0[p1]+y1[p1])  (f32 out) ----------------
__global__ __launch_bounds__(256) void final_kernel(const float* __restrict__ x1,
        const float* __restrict__ yp0, const float* __restrict__ yp1, const int* __restrict__ pos,
        const float2* __restrict__ gate, float* __restrict__ out) {
    int t = blockIdx.x, tid = threadIdx.x;
    float2 g = gate[t];
    int p0 = pos[t * 2], p1 = pos[t * 2 + 1];
#pragma unroll
    for (int i = 0; i < 3; i++) {
        int d = tid + i * 256;
        float y0 = yp0[(size_t)p0 * 768 + d] + yp1[(size_t)p0 * 768 + d];
        float y1 = yp0[(size_t)p1 * 768 + d] + yp1[(size_t)p1 * 768 + d];
        out[(size_t)t * 768 + d] = x1[(size_t)t * 768 + d] + g.x * y0 + g.y * y1;
    }
}

extern "C" void kernel_launch(void* const* d_in, const int* in_sizes, int n_in,
                              void* d_out, int out_size, void* d_ws, size_t ws_size,
                              hipStream_t stream) {
    const float* x      = (const float*)d_in[0];
    const float* ln1_g  = (const float*)d_in[1];
    const float* ln1_b  = (const float*)d_in[2];
    const float* qkv_w  = (const float*)d_in[3];
    const float* qkv_b  = (const float*)d_in[4];
    const float* proj_w = (const float*)d_in[5];
    const float* proj_b = (const float*)d_in[6];
    const float* ln2_g  = (const float*)d_in[7];
    const float* ln2_b  = (const float*)d_in[8];
    const float* w_gate = (const float*)d_in[9];
    const float* w1     = (const float*)d_in[10];
    const float* b1     = (const float*)d_in[11];
    const float* w2     = (const float*)d_in[12];
    const float* b2     = (const float*)d_in[13];

    char* ws = (char*)d_ws;
    size_t off = 0;
    auto alloc = [&](size_t bytes) { size_t cur = off; off = (off + bytes + 255) & ~(size_t)255; return cur; };
    // region0: h_hi|h_lo|qkv_hi|qkv_lo|o_hi|o_lo (dead before MoE2) — reused as ypair0 (25.9MB <= 48.4MB)
    u16*    h_hi   = (u16*)   (ws + alloc((size_t)T_TOK * 768 * 2));
    u16*    h_lo   = (u16*)   (ws + alloc((size_t)T_TOK * 768 * 2));
    u16*    qkv_hi = (u16*)   (ws + alloc((size_t)T_TOK * 2304 * 2));
    u16*    qkv_lo = (u16*)   (ws + alloc((size_t)T_TOK * 2304 * 2));
    u16*    o_hi   = (u16*)   (ws + alloc((size_t)T_TOK * 768 * 2));
    u16*    o_lo   = (u16*)   (ws + alloc((size_t)T_TOK * 768 * 2));
    float*  ypair0 = (float*) ws;   // 8448*768*4 = 25.9MB <= region0
    float*  x1     = (float*) (ws + alloc((size_t)T_TOK * 768 * 4));
    u16*    flat   = (u16*)   (ws + alloc((size_t)T_TOK * 768 * 2));
    int2*   idx    = (int2*)  (ws + alloc((size_t)T_TOK * 8));
    float2* gate   = (float2*)(ws + alloc((size_t)T_TOK * 8));
    int*    cnt    = (int*)   (ws + alloc(64));     // cnt[8] + cursor[8]
    int*    cursor = cnt + 8;
    int*    asg    = (int*)   (ws + alloc(64));     // aligned_start[9]
    int*    list   = (int*)   (ws + alloc((size_t)LISTN * 4));
    int*    pos    = (int*)   (ws + alloc((size_t)T_TOK * 2 * 4));
    u16*    hid    = (u16*)   (ws + alloc((size_t)LISTN * 3072 * 2));
    u16*    qkvt_h = (u16*)   (ws + alloc((size_t)2304 * 768 * 2));
    u16*    qkvt_l = (u16*)   (ws + alloc((size_t)2304 * 768 * 2));
    u16*    projt_h = (u16*)  (ws + alloc((size_t)768 * 768 * 2));
    u16*    projt_l = (u16*)  (ws + alloc((size_t)768 * 768 * 2));
    u16*    w1t    = (u16*)   (ws + alloc((size_t)8 * 3072 * 768 * 2));
    u16*    w2t    = (u16*)   (ws + alloc((size_t)8 * 768 * 3072 * 2));
    float*  ypair1 = (float*) w1t;  // w1t (37.7MB) dead after moe1; ypair1 needs 25.9MB

    hipMemsetAsync(cnt, 0, 64, stream);
    hipMemsetAsync(list, 0xFF, (size_t)LISTN * 4, stream);

    // weight prep (bf16, [n][k] layout; qkv/proj split hi/lo)
    transp_kernel<1><<<dim3(12, 36, 1), 256, 0, stream>>>(qkv_w, qkvt_h, qkvt_l, 768, 2304);
    transp_kernel<1><<<dim3(12, 12, 1), 256, 0, stream>>>(proj_w, projt_h, projt_l, 768, 768);
    transp_kernel<0><<<dim3(12, 48, 8), 256, 0, stream>>>(w1, w1t, nullptr, 768, 3072);
    transp_kernel<0><<<dim3(48, 12, 8), 256, 0, stream>>>(w2, w2t, nullptr, 3072, 768);

    ln1_kernel<<<T_TOK, 256, 0, stream>>>(x, ln1_g, ln1_b, h_hi, h_lo);
    gemm128<0><<<dim3(25, 18), 256, 0, stream>>>(h_hi, h_lo, qkvt_h, qkvt_l, qkv_b, qkv_hi,
                                                 qkv_lo, nullptr, nullptr, nullptr, T_TOK, 2304, 768);
    attn_mfma_kernel<<<dim3(4, 192), 256, 0, stream>>>(qkv_hi, qkv_lo, o_hi, o_lo);
    gemm128<1><<<dim3(25, 6), 256, 0, stream>>>(o_hi, o_lo, projt_h, projt_l, proj_b, x1,
                                                nullptr, x, nullptr, nullptr, T_TOK, 768, 768);
    ln2_gate_kernel<<<T_TOK, 256, 0, stream>>>(x1, ln2_g, ln2_b, w_gate, flat, idx, gate);
    hist_kernel<<<(T_TOK + 255) / 256, 256, 0, stream>>>(idx, cnt);
    offsets_kernel<<<1, 64, 0, stream>>>(cnt, asg);
    scatter_kernel<<<(T_TOK + 255) / 256, 256, 0, stream>>>(idx, asg, cursor, list, pos);
    gemm256_moe1<<<dim3(MOE1_MT, 12), 512, 0, stream>>>(flat, w1t, b1, hid, list, asg);
    gemm128<3><<<dim3(MOE2_MT, 6, 2), 256, 0, stream>>>(hid, nullptr, w2t, nullptr, b2, ypair0,
                                                        ypair1, nullptr, list, asg, LISTN, 768, 3072);
    final_kernel<<<T_TOK, 256, 0, stream>>>(x1, ypair0, ypair1, pos, gate, (float*)d_out);
}

// Round 8
// 591.099 us; speedup vs baseline: 1.1062x; 1.1062x over previous
//
#include <hip/hip_runtime.h>
#include <math.h>
#include <stdint.h>

typedef unsigned short u16;
typedef unsigned int u32;
typedef float floatx4 __attribute__((ext_vector_type(4)));
typedef __bf16 bf16x8 __attribute__((ext_vector_type(8)));

#define T_TOK 3152      // B*L = 16*197
#define SEQ 197
#define NH 12
#define LISTN 7424      // 58 tiles * 128 (worst-case 128-aligned expert segments)
#define MOE_MT 58
#define YHALF ((size_t)LISTN * 768)

__device__ __forceinline__ float bf2f(u16 u) { return __uint_as_float(((u32)u) << 16); }
__device__ __forceinline__ u16 f2bf(float f) {
    u32 u = __float_as_uint(f);
    u += 0x7FFFu + ((u >> 16) & 1u);   // RNE
    return (u16)(u >> 16);
}
__device__ __forceinline__ float wred_sum(float v) {
#pragma unroll
    for (int off = 32; off; off >>= 1) v += __shfl_xor(v, off);
    return v;
}

// fast exact-enough gelu: A&S 7.1.26 erf, |err| <= 1.5e-7 (abs) -> bf16-identical vs erff
__device__ __forceinline__ float gelu_fast(float v) {
    float x = fabsf(v) * 0.70710678118654752f;
    float t = __builtin_amdgcn_rcpf(fmaf(0.3275911f, x, 1.0f));
    float p = t * fmaf(t, fmaf(t, fmaf(t, fmaf(t, 1.061405429f, -1.453152027f),
                                       1.421413741f), -0.284496736f), 0.254829592f);
    float er = fmaf(-p, __expf(-x * x), 1.0f);   // erf(|x|)
    er = copysignf(er, v);
    return 0.5f * v * (1.0f + er);
}

// async global->LDS, 16B per lane; LDS dest must be wave-uniform base (+lane*16 implicit)
#define GLB_AS(p) ((const __attribute__((address_space(1))) void*)(uintptr_t)(p))
#define LDS_AS(p) ((__attribute__((address_space(3))) void*)(uintptr_t)(p))
__device__ __forceinline__ void gl_lds16(const u16* g, u16* l) {
    __builtin_amdgcn_global_load_lds(GLB_AS(g), LDS_AS(l), 16, 0, 0);
}

// ---------------- weight prep: in f32 [z][R][C] -> out bf16 [z][C][R] (opt split hi/lo) ----------------
template <int SPLIT>
__global__ __launch_bounds__(256) void transp_kernel(const float* __restrict__ in,
        u16* __restrict__ oh, u16* __restrict__ ol, int R, int C) {
    int r0 = blockIdx.x * 64, c0 = blockIdx.y * 64;
    size_t zo = (size_t)blockIdx.z * R * C;
    __shared__ float Lt[64][68];
    int tid = threadIdx.x;
    int rr = tid >> 2, cs = (tid & 3) * 16;
    const float* src = in + zo + (size_t)(r0 + rr) * C + c0 + cs;
#pragma unroll
    for (int i = 0; i < 4; i++) *(float4*)&Lt[rr][cs + i * 4] = *(const float4*)(src + i * 4);
    __syncthreads();
    int cw = tid >> 2, rs = (tid & 3) * 16;
    u16 hv[16], lv[16];
#pragma unroll
    for (int j = 0; j < 16; j++) {
        float v = Lt[rs + j][cw];
        u16 hb = f2bf(v);
        hv[j] = hb;
        if (SPLIT) lv[j] = f2bf(v - bf2f(hb));
    }
    u16* dst = oh + zo + (size_t)(c0 + cw) * R + r0 + rs;
    *(uint4*)dst = *(const uint4*)&hv[0];
    *(uint4*)(dst + 8) = *(const uint4*)&hv[8];
    if (SPLIT) {
        u16* dstl = ol + zo + (size_t)(c0 + cw) * R + r0 + rs;
        *(uint4*)dstl = *(const uint4*)&lv[0];
        *(uint4*)(dstl + 8) = *(const uint4*)&lv[8];
    }
}

// ---------------- LN1: h = LN(x)*g+b, split to bf16 hi/lo planes ----------------
__global__ __launch_bounds__(256) void ln1_kernel(const float* __restrict__ x,
        const float* __restrict__ g, const float* __restrict__ b,
        u16* __restrict__ h_hi, u16* __restrict__ h_lo) {
    int t = blockIdx.x, tid = threadIdx.x;
    int w = tid >> 6, lane = tid & 63;
    float v[3];
#pragma unroll
    for (int i = 0; i < 3; i++) v[i] = x[(size_t)t * 768 + tid + i * 256];
    float s = v[0] + v[1] + v[2];
    float q = v[0] * v[0] + v[1] * v[1] + v[2] * v[2];
    s = wred_sum(s); q = wred_sum(q);
    __shared__ float red[8];
    if (lane == 0) { red[w] = s; red[4 + w] = q; }
    __syncthreads();
    float st = red[0] + red[1] + red[2] + red[3];
    float qt = red[4] + red[5] + red[6] + red[7];
    float mean = st * (1.f / 768.f);
    float var = qt * (1.f / 768.f) - mean * mean;
    float rs = rsqrtf(var + 1e-5f);
#pragma unroll
    for (int i = 0; i < 3; i++) {
        int d = tid + i * 256;
        float hv = (v[i] - mean) * rs * g[d] + b[d];
        u16 hi = f2bf(hv);
        h_hi[(size_t)t * 768 + d] = hi;
        h_lo[(size_t)t * 768 + d] = f2bf(hv - bf2f(hi));
    }
}

// ---------------- 128x128 MFMA GEMM (modes 0/1/3) ----------------
// global_load_lds staging. SPLIT modes (0/1): double-buffer + drain (48 MFMA/step covers latency).
// MODE 3: TRIPLE-buffer counted-vmcnt pipeline (r4-proven 48KB config).
// XCD-partitioned bijective grid swizzle. B pre-transposed bf16 [n][k].
// MODE 0: qkv split -> bf16 hi/lo planes (Cv/Cv2). MODE 1: proj split + resid -> f32.
// MODE 3: moe2 dense A -> f32, split-K; z=0 -> Cv, z=1 -> Cv2 (separate buffers).
template <int MODE>
__global__ __launch_bounds__(256) void gemm128(const u16* __restrict__ Ah,
        const u16* __restrict__ Al, const u16* __restrict__ Bh, const u16* __restrict__ Bl,
        const float* __restrict__ bias, void* __restrict__ Cv, void* __restrict__ Cv2,
        const float* __restrict__ resid,
        const int* __restrict__ list, const int* __restrict__ asg, int M, int N, int K) {
    constexpr bool SPLIT = (MODE <= 1);
    constexpr int GX = (MODE <= 1) ? 25 : MOE_MT;                    // m-tiles
    constexpr int GY = (MODE == 0) ? 18 : 6;                         // n-tiles
    constexpr int GZ = (MODE == 3) ? 2 : 1;                          // split-K
    constexpr int G  = GX * GY * GZ;
    constexpr int NT = GY * GZ;
    constexpr int Q8 = G >> 3, R8 = G & 7;

    // dispatch index -> XCD-contiguous tile id (bijective, m204 form); HW round-robins d%8 over XCDs
    int d = blockIdx.x + GX * (blockIdx.y + GY * blockIdx.z);
    int j = d & 7, s = d >> 3;
    int v = (j < R8) ? (j * (Q8 + 1) + s) : (R8 * (Q8 + 1) + (j - R8) * Q8 + s);
    int mt = v / NT, nzr = v - mt * NT;
    int yt = nzr % GY, zt = nzr / GY;
    int m0 = mt * 128, n0 = yt * 128;

    const u16* Bph = Bh;
    const float* bp = bias;
    const u16* Bpl = Bl;
    if (MODE == 3) {
        if (m0 >= asg[8]) return;
        int e = 0;
        while (m0 >= asg[e + 1]) ++e;    // uniform across block
        Bph = Bh + (size_t)e * N * K;
        bp = bias + (size_t)e * N;
    }
    int kbeg = 0, kend = K;
    if (MODE == 3) { int kh = K >> 1; kbeg = zt * kh; kend = kbeg + kh; }

    // LDS pool. SPLIT: 2 bufs x {Ah,Bh,Al,Bl} x 8KB = 64KB. MODE3: 3 bufs x {A,B} x 8KB = 48KB.
    __shared__ __align__(16) u16 SM[SPLIT ? 32768 : 24576];
    u16* Ash = SM;
    u16* Bsh = SM + (SPLIT ? 8192 : 12288);
    u16* Asl = SM + 16384;   // SPLIT only
    u16* Bsl = SM + 24576;   // SPLIT only

    int tid = threadIdx.x;
    int w = tid >> 6, lane = tid & 63, l15 = lane & 15, quad = lane >> 4;
    int wm = (w & 1) * 64, wn = (w >> 1) * 64;
    int lr = lane >> 2;
    // source granule swizzle: LDS slot (row=lane>>2, gpos=lane&3) holds logical granule
    // gpos ^ ((row>>1)&3); since (lane>>3)&3 == (tile_row>>1)&3 this is per-lane source math only.
    int lc = ((lane & 3) ^ ((lane >> 3) & 3)) * 8;

    const u16* ga[2]; const u16* gal[2];
    const u16* gb[2]; const u16* gbl[2];
    int ldro[2];
#pragma unroll
    for (int it = 0; it < 2; it++) {
        int arow = m0 + it * 64 + w * 16 + lr;
        if (MODE == 3) {
            ga[it] = Ah + (size_t)arow * K + lc;   // padding rows finite poison; store-guarded
        } else {
            int rc = min(arow, M - 1);
            ga[it] = Ah + (size_t)rc * K + lc;
            gal[it] = Al + (size_t)rc * K + lc;
        }
        int brow = n0 + it * 64 + w * 16 + lr;
        gb[it] = Bph + (size_t)brow * K + lc;
        if (SPLIT) gbl[it] = Bpl + (size_t)brow * K + lc;
        ldro[it] = (it * 64 + w * 16) * 32;       // wave-uniform LDS chunk base (within a buffer)
    }

    // read addresses (loop-invariant): row-major [128][32] with XOR granule de-swizzle
    int ra[4], rb[4];
#pragma unroll
    for (int i = 0; i < 4; i++) {
        int r1 = wm + i * 16 + l15;
        ra[i] = r1 * 32 + (quad ^ ((r1 >> 1) & 3)) * 8;
        int r2 = wn + i * 16 + l15;
        rb[i] = r2 * 32 + (quad ^ ((r2 >> 1) & 3)) * 8;
    }

    floatx4 acc[4][4];
#pragma unroll
    for (int mi = 0; mi < 4; mi++)
#pragma unroll
        for (int ni = 0; ni < 4; ni++) acc[mi][ni] = (floatx4){0.f, 0.f, 0.f, 0.f};

    auto stage = [&](int buf, int k0) {
        int bo = buf * 4096;
#pragma unroll
        for (int it = 0; it < 2; it++) {
            gl_lds16(ga[it] + k0, &Ash[bo + ldro[it]]);
            gl_lds16(gb[it] + k0, &Bsh[bo + ldro[it]]);
            if constexpr (SPLIT) {
                gl_lds16(gal[it] + k0, &Asl[bo + ldro[it]]);
                gl_lds16(gbl[it] + k0, &Bsl[bo + ldro[it]]);
            }
        }
    };
    auto compute = [&](int buf) {
        int bo = buf * 4096;
        bf16x8 afh[4], bfh[4], afl[4], bfl[4];
#pragma unroll
        for (int i = 0; i < 4; i++) {
            afh[i] = *(const bf16x8*)&Ash[bo + ra[i]];
            bfh[i] = *(const bf16x8*)&Bsh[bo + rb[i]];
            if constexpr (SPLIT) {
                afl[i] = *(const bf16x8*)&Asl[bo + ra[i]];
                bfl[i] = *(const bf16x8*)&Bsl[bo + rb[i]];
            }
        }
        if constexpr (!SPLIT) __builtin_amdgcn_s_setprio(1);
#pragma unroll
        for (int mi = 0; mi < 4; mi++)
#pragma unroll
            for (int ni = 0; ni < 4; ni++) {
                if constexpr (SPLIT) {
                    acc[mi][ni] = __builtin_amdgcn_mfma_f32_16x16x32_bf16(afl[mi], bfh[ni], acc[mi][ni], 0, 0, 0);
                    acc[mi][ni] = __builtin_amdgcn_mfma_f32_16x16x32_bf16(afh[mi], bfl[ni], acc[mi][ni], 0, 0, 0);
                }
                acc[mi][ni] = __builtin_amdgcn_mfma_f32_16x16x32_bf16(afh[mi], bfh[ni], acc[mi][ni], 0, 0, 0);
            }
        if constexpr (!SPLIT) __builtin_amdgcn_s_setprio(0);
    };

    int nsteps = (kend - kbeg) >> 5;
    if constexpr (SPLIT) {
        stage(0, kbeg);
        __syncthreads();
        for (int s2 = 0; s2 < nsteps; s2 += 2) {
            int k0 = kbeg + s2 * 32;
            stage(1, k0 + 32);
            compute(0);
            __syncthreads();
            if (s2 + 2 < nsteps) stage(0, k0 + 64);
            compute(1);
            __syncthreads();
        }
    } else {
        // depth-3 counted-vmcnt pipeline (r4-proven); 4 gl_lds per stage per wave.
        stage(0, kbeg);
        stage(1, kbeg + 32);
        asm volatile("s_waitcnt vmcnt(4)" ::: "memory");   // buf0 landed (buf1 = 4 in flight)
        __builtin_amdgcn_s_barrier();
        int bufc = 0;
        for (int t = 0; t < nsteps; ++t) {
            int b2 = bufc + 2; if (b2 >= 3) b2 -= 3;
            if (t + 2 < nsteps) stage(b2, kbeg + (t + 2) * 32);   // overwrites buf(t-1): freed by prev barrier
            compute(bufc);
            if (t + 2 < nsteps) {
                asm volatile("s_waitcnt vmcnt(4) lgkmcnt(0)" ::: "memory");
            } else {
                asm volatile("s_waitcnt vmcnt(0) lgkmcnt(0)" ::: "memory");
            }
            __builtin_amdgcn_s_barrier();
            bufc = (bufc == 2) ? 0 : bufc + 1;
        }
    }

    float* Cf = (float*)Cv;
    if (MODE == 3 && zt != 0) Cf = (float*)Cv2;
#pragma unroll
    for (int ni = 0; ni < 4; ni++) {
        int col = n0 + wn + ni * 16 + l15;
        float bb = bp[col];
        if (MODE == 3 && zt != 0) bb = 0.f;   // bias added once (z=0 half)
#pragma unroll
        for (int mi = 0; mi < 4; mi++) {
#pragma unroll
            for (int r = 0; r < 4; r++) {
                int row = m0 + wm + mi * 16 + quad * 4 + r;
                float v2 = acc[mi][ni][r] + bb;
                if (MODE == 0) {
                    if (row < M) {
                        u16 hb = f2bf(v2);
                        ((u16*)Cv)[(size_t)row * N + col] = hb;
                        ((u16*)Cv2)[(size_t)row * N + col] = f2bf(v2 - bf2f(hb));
                    }
                } else if (MODE == 1) {
                    if (row < M) Cf[(size_t)row * N + col] = v2 + resid[(size_t)row * N + col];
                } else {
                    if (list[row] >= 0) Cf[(size_t)row * N + col] = v2;
                }
            }
        }
    }
}

// ---------------- moe1: 128x256 tile, 4 waves, depth-3 counted-vmcnt (r4 skeleton, wider N) ----------------
// Per step per wave: 6 gl_lds (A 2, B 4), 12 ds_read_b128, 32 MFMA — 2x compute density of 128x128,
// and A-panel re-reads halve (12 n-blocks instead of 24). Grid 58x12 = 696 blocks.
__global__ __launch_bounds__(256) void gemm_moe1(const u16* __restrict__ Ah,
        const u16* __restrict__ Bh, const float* __restrict__ bias, u16* __restrict__ Cv,
        const int* __restrict__ list, const int* __restrict__ asg) {
    constexpr int GX = MOE_MT, GY = 12, G = GX * GY;   // 696
    constexpr int Q8 = G >> 3, R8 = G & 7;
    constexpr int N = 3072, K = 768, NSTEP = 24;

    int d = blockIdx.x + GX * blockIdx.y;
    int j = d & 7, s = d >> 3;
    int v = (j < R8) ? (j * (Q8 + 1) + s) : (R8 * (Q8 + 1) + (j - R8) * Q8 + s);
    int mt = v / GY, yt = v - mt * GY;
    int m0 = mt * 128, n0 = yt * 256;
    if (m0 >= asg[8]) return;
    int e = 0;
    while (m0 >= asg[e + 1]) ++e;        // 128-aligned segments: uniform expert per block
    const u16* Bph = Bh + (size_t)e * N * K;
    const float* bp = bias + (size_t)e * N;

    // LDS: A[3 bufs][4096 u16] @0 (24KB), B[3 bufs][8192 u16] @12288 (48KB) = 72KB pool.
    // Epilogue reuses first 64KB as a [128][256] bf16 C-tile.
    __shared__ __align__(16) u16 SM[36864];
    u16* Ash = SM;
    u16* Bsh = SM + 12288;

    int tid = threadIdx.x;
    int w = tid >> 6, lane = tid & 63, l15 = lane & 15, quad = lane >> 4;
    int wm = (w & 1) * 64, wn = (w >> 1) * 128;
    int lr = lane >> 2;
    int lc = ((lane & 3) ^ ((lane >> 3) & 3)) * 8;   // source granule swizzle

    const u16* ga[2]; const u16* gb[4];
    int ldro[4];
#pragma unroll
    for (int it = 0; it < 2; it++) {
        int arow = m0 + it * 64 + w * 16 + lr;
        int entry = list[arow];
        ga[it] = Ah + (size_t)(entry >= 0 ? (entry >> 1) : 0) * K + lc;  // invalid -> row0, store-guarded
    }
#pragma unroll
    for (int it = 0; it < 4; it++) {
        int brow = n0 + it * 64 + w * 16 + lr;
        gb[it] = Bph + (size_t)brow * K + lc;
        ldro[it] = (it * 64 + w * 16) * 32;
    }

    int ra[4], rb[8];
#pragma unroll
    for (int i = 0; i < 4; i++) {
        int r1 = wm + i * 16 + l15;
        ra[i] = r1 * 32 + (quad ^ ((r1 >> 1) & 3)) * 8;
    }
#pragma unroll
    for (int i = 0; i < 8; i++) {
        int r2 = wn + i * 16 + l15;
        rb[i] = r2 * 32 + (quad ^ ((r2 >> 1) & 3)) * 8;
    }

    floatx4 acc[4][8];
#pragma unroll
    for (int mi = 0; mi < 4; mi++)
#pragma unroll
        for (int ni = 0; ni < 8; ni++) acc[mi][ni] = (floatx4){0.f, 0.f, 0.f, 0.f};

    auto stage = [&](int buf, int k0) {
#pragma unroll
        for (int it = 0; it < 2; it++) gl_lds16(ga[it] + k0, &Ash[buf * 4096 + ldro[it]]);
#pragma unroll
        for (int it = 0; it < 4; it++) gl_lds16(gb[it] + k0, &Bsh[buf * 8192 + ldro[it]]);
    };
    auto compute = [&](int buf) {
        const u16* la = &Ash[buf * 4096];
        const u16* lb = &Bsh[buf * 8192];
        bf16x8 af[4];
#pragma unroll
        for (int i = 0; i < 4; i++) af[i] = *(const bf16x8*)&la[ra[i]];
        __builtin_amdgcn_s_setprio(1);
#pragma unroll
        for (int half = 0; half < 2; half++) {
            bf16x8 bf[4];
#pragma unroll
            for (int i = 0; i < 4; i++) bf[i] = *(const bf16x8*)&lb[rb[half * 4 + i]];
#pragma unroll
            for (int mi = 0; mi < 4; mi++)
#pragma unroll
                for (int ni = 0; ni < 4; ni++)
                    acc[mi][half * 4 + ni] =
                        __builtin_amdgcn_mfma_f32_16x16x32_bf16(af[mi], bf[ni], acc[mi][half * 4 + ni], 0, 0, 0);
        }
        __builtin_amdgcn_s_setprio(0);
    };

    stage(0, 0);
    stage(1, 32);
    asm volatile("s_waitcnt vmcnt(6)" ::: "memory");   // buf0's 6 landed (buf1's 6 in flight)
    __builtin_amdgcn_s_barrier();
    int bufc = 0;
    for (int t = 0; t < NSTEP; ++t) {
        int b2 = bufc + 2; if (b2 >= 3) b2 -= 3;
        if (t + 2 < NSTEP) stage(b2, (t + 2) * 32);    // overwrites buf(t-1): freed by prev barrier
        compute(bufc);
        if (t + 2 < NSTEP) {
            asm volatile("s_waitcnt vmcnt(6) lgkmcnt(0)" ::: "memory");
        } else {
            asm volatile("s_waitcnt vmcnt(0) lgkmcnt(0)" ::: "memory");
        }
        __builtin_amdgcn_s_barrier();
        bufc = (bufc == 2) ? 0 : bufc + 1;
    }

    // epilogue: gelu -> SM[128][256] bf16 (64KB, col XOR-swizzled), then coalesced row stores
#pragma unroll
    for (int ni = 0; ni < 8; ni++) {
        int col = wn + ni * 16 + l15;
        float bb = bp[n0 + col];
#pragma unroll
        for (int mi = 0; mi < 4; mi++) {
#pragma unroll
            for (int r = 0; r < 4; r++) {
                int row = wm + mi * 16 + quad * 4 + r;
                SM[row * 256 + (col ^ ((row & 7) << 3))] = f2bf(gelu_fast(acc[mi][ni][r] + bb));
            }
        }
    }
    __syncthreads();
    int rr = tid >> 1, half = (tid & 1) * 128;
    int grow = m0 + rr;
    if (list[grow] >= 0) {
        u16* dst = Cv + (size_t)grow * N + n0 + half;
        int xr = (rr & 7) << 3;
#pragma unroll
        for (int gch = 0; gch < 16; gch++) {
            int cb = (half + gch * 8) ^ xr;
            *(uint4*)(dst + gch * 8) = *(const uint4*)&SM[rr * 256 + cb];
        }
    }
}

// ---------------- MFMA attention: bf16 hi/lo qkv planes; block = (b, h, 64-q-tile), 4 waves ----------------
__global__ __launch_bounds__(256) void attn_mfma_kernel(const u16* __restrict__ qph,
        const u16* __restrict__ qpl, u16* __restrict__ ohi, u16* __restrict__ olo) {
    // bijective XCD swizzle over 768 blocks: XCD j gets 24 consecutive (b,h) with all 4 q-tiles
    int d = blockIdx.x + 4 * blockIdx.y;
    int j = d & 7, sdx = d >> 3;
    int v = j * 96 + sdx;
    int qbase = (v & 3) * 64;
    int by = v >> 2;
    int b = by / NH, h = by % NH;
    int tid = threadIdx.x;
    int w = tid >> 6, lane = tid & 63, l15 = lane & 15, quad = lane >> 4;

    __shared__ u16 Qh[64 * 64], Ql[64 * 64];
    __shared__ u16 Sh[64 * 64], Sl[64 * 64];   // K tile, then V^T tile
    __shared__ u16 Ph[64 * 72], Pl[64 * 72];

    int grow8 = lane >> 3;                     // row within 8-row gl_lds group
    int gsrc = ((lane & 7) ^ grow8) * 8;       // swizzled source granule (u16 offset)
    int srow = tid >> 2;                       // V^T: key index
    int scol = (tid & 3) * 16;                 // V^T: d base

    // --- stage Q (gl_lds, swizzled) ---
#pragma unroll
    for (int it = 0; it < 2; it++) {
        int r = qbase + w * 16 + it * 8 + grow8;
        int rc = min(r, SEQ - 1);
        size_t so = (size_t)(b * SEQ + rc) * 2304 + h * 64 + gsrc;
        gl_lds16(qph + so, &Qh[(w * 16 + it * 8) * 64]);
        gl_lds16(qpl + so, &Ql[(w * 16 + it * 8) * 64]);
    }
    __syncthreads();
    bf16x8 aqh[2], aql[2];
#pragma unroll
    for (int s2 = 0; s2 < 2; s2++) {
        int row = w * 16 + l15;
        int ad = row * 64 + (((s2 * 4 + quad) ^ (row & 7))) * 8;
        aqh[s2] = *(const bf16x8*)&Qh[ad];
        aql[s2] = *(const bf16x8*)&Ql[ad];
    }

    floatx4 sc[16];
#pragma unroll
    for (int f = 0; f < 16; f++) sc[f] = (floatx4){0.f, 0.f, 0.f, 0.f};

    for (int t = 0; t < 4; t++) {
#pragma unroll
        for (int it = 0; it < 2; it++) {
            int r = t * 64 + w * 16 + it * 8 + grow8;
            int rc = min(r, SEQ - 1);
            size_t so = (size_t)(b * SEQ + rc) * 2304 + 768 + h * 64 + gsrc;
            gl_lds16(qph + so, &Sh[(w * 16 + it * 8) * 64]);
            gl_lds16(qpl + so, &Sl[(w * 16 + it * 8) * 64]);
        }
        __syncthreads();
#pragma unroll
        for (int s = 0; s < 4; s++) {
            int row = s * 16 + l15;
#pragma unroll
            for (int s2 = 0; s2 < 2; s2++) {
                int ad = row * 64 + (((s2 * 4 + quad) ^ (row & 7))) * 8;
                bf16x8 bkh = *(const bf16x8*)&Sh[ad];
                bf16x8 bkl = *(const bf16x8*)&Sl[ad];
                sc[t * 4 + s] = __builtin_amdgcn_mfma_f32_16x16x32_bf16(aql[s2], bkh, sc[t * 4 + s], 0, 0, 0);
                sc[t * 4 + s] = __builtin_amdgcn_mfma_f32_16x16x32_bf16(aqh[s2], bkl, sc[t * 4 + s], 0, 0, 0);
                sc[t * 4 + s] = __builtin_amdgcn_mfma_f32_16x16x32_bf16(aqh[s2], bkh, sc[t * 4 + s], 0, 0, 0);
            }
        }
        __syncthreads();
    }

    float m[4] = {-1e30f, -1e30f, -1e30f, -1e30f};
#pragma unroll
    for (int f = 0; f < 16; f++) {
        int key = (f >> 2) * 64 + (f & 3) * 16 + l15;
        bool valid = key < SEQ;
#pragma unroll
        for (int r = 0; r < 4; r++) {
            float s = valid ? sc[f][r] * 0.125f : -1e30f;
            sc[f][r] = s;
            m[r] = fmaxf(m[r], s);
        }
    }
#pragma unroll
    for (int r = 0; r < 4; r++) {
#pragma unroll
        for (int off = 1; off < 16; off <<= 1) m[r] = fmaxf(m[r], __shfl_xor(m[r], off));
    }
    float sum[4] = {0.f, 0.f, 0.f, 0.f};
#pragma unroll
    for (int f = 0; f < 16; f++) {
#pragma unroll
        for (int r = 0; r < 4; r++) {
            float p = expf(sc[f][r] - m[r]);
            sc[f][r] = p;
            sum[r] += p;
        }
    }
    float inv[4];
#pragma unroll
    for (int r = 0; r < 4; r++) {
#pragma unroll
        for (int off = 1; off < 16; off <<= 1) sum[r] += __shfl_xor(sum[r], off);
        inv[r] = 1.f / sum[r];
    }

    floatx4 oacc[4];
#pragma unroll
    for (int sd = 0; sd < 4; sd++) oacc[sd] = (floatx4){0.f, 0.f, 0.f, 0.f};

    for (int t = 0; t < 4; t++) {
#pragma unroll
        for (int s = 0; s < 4; s++) {
#pragma unroll
            for (int r = 0; r < 4; r++) {
                float p = sc[t * 4 + s][r];
                u16 hb = f2bf(p);
                int row = w * 16 + quad * 4 + r;
                Ph[row * 72 + s * 16 + l15] = hb;
                Pl[row * 72 + s * 16 + l15] = f2bf(p - bf2f(hb));
            }
        }
        {
            // V^T staging from bf16 planes (u16-only), granule-swizzled for conflict-free reads
            int key = t * 64 + srow;
            int kc = min(key, SEQ - 1);   // garbage rows hit P==0 (masked scores), finite => safe
            size_t so = (size_t)(b * SEQ + kc) * 2304 + 1536 + h * 64 + scol;
            u16 hv[16], lv[16];
            *(uint4*)&hv[0] = *(const uint4*)(qph + so);
            *(uint4*)&hv[8] = *(const uint4*)(qph + so + 8);
            *(uint4*)&lv[0] = *(const uint4*)(qpl + so);
            *(uint4*)&lv[8] = *(const uint4*)(qpl + so + 8);
            int kg = srow >> 3, kw = srow & 7;
#pragma unroll
            for (int i = 0; i < 16; i++) {
                int dcol = scol + i;
                int idx = dcol * 64 + ((kg ^ (dcol & 7)) * 8) + kw;
                Sh[idx] = hv[i];
                Sl[idx] = lv[i];
            }
        }
        __syncthreads();
#pragma unroll
        for (int s2 = 0; s2 < 2; s2++) {
            bf16x8 aph = *(const bf16x8*)&Ph[(w * 16 + l15) * 72 + s2 * 32 + quad * 8];
            bf16x8 apl = *(const bf16x8*)&Pl[(w * 16 + l15) * 72 + s2 * 32 + quad * 8];
#pragma unroll
            for (int sd = 0; sd < 4; sd++) {
                int row = sd * 16 + l15;
                int ad = row * 64 + (((s2 * 4 + quad) ^ (row & 7))) * 8;
                bf16x8 bvh = *(const bf16x8*)&Sh[ad];
                bf16x8 bvl = *(const bf16x8*)&Sl[ad];
                oacc[sd] = __builtin_amdgcn_mfma_f32_16x16x32_bf16(apl, bvh, oacc[sd], 0, 0, 0);
                oacc[sd] = __builtin_amdgcn_mfma_f32_16x16x32_bf16(aph, bvl, oacc[sd], 0, 0, 0);
                oacc[sd] = __builtin_amdgcn_mfma_f32_16x16x32_bf16(aph, bvh, oacc[sd], 0, 0, 0);
            }
        }
        __syncthreads();
    }

#pragma unroll
    for (int sd = 0; sd < 4; sd++) {
#pragma unroll
        for (int r = 0; r < 4; r++) {
            int q = qbase + w * 16 + quad * 4 + r;
            if (q < SEQ) {
                float val = oacc[sd][r] * inv[r];
                u16 hb = f2bf(val);
                size_t o = ((size_t)(b * SEQ + q)) * 768 + h * 64 + sd * 16 + l15;
                ohi[o] = hb;
                olo[o] = f2bf(val - bf2f(hb));
            }
        }
    }
}

// ---------------- LN2 + gate (top-2 of 8) + fused histogram ----------------
__global__ __launch_bounds__(256) void ln2_gate_kernel(const float* __restrict__ x1,
        const float* __restrict__ g, const float* __restrict__ b, const float* __restrict__ wg,
        u16* __restrict__ flat, int2* __restrict__ idx, float2* __restrict__ gate,
        int* __restrict__ cnt) {
    int t = blockIdx.x, tid = threadIdx.x;
    int w = tid >> 6, lane = tid & 63;
    float v[3];
#pragma unroll
    for (int i = 0; i < 3; i++) v[i] = x1[(size_t)t * 768 + tid + i * 256];
    float s = v[0] + v[1] + v[2];
    float q = v[0] * v[0] + v[1] * v[1] + v[2] * v[2];
    s = wred_sum(s); q = wred_sum(q);
    __shared__ float red[8];
    __shared__ float fs[768];
    __shared__ float lg[8];
    if (lane == 0) { red[w] = s; red[4 + w] = q; }
    __syncthreads();
    float st = red[0] + red[1] + red[2] + red[3];
    float qt = red[4] + red[5] + red[6] + red[7];
    float mean = st * (1.f / 768.f);
    float var = qt * (1.f / 768.f) - mean * mean;
    float rs = rsqrtf(var + 1e-5f);
#pragma unroll
    for (int i = 0; i < 3; i++) {
        int d = tid + i * 256;
        float f = (v[i] - mean) * rs * g[d] + b[d];
        flat[(size_t)t * 768 + d] = f2bf(f);
        fs[d] = f;
    }
    __syncthreads();
    int e0 = 2 * w, e1 = 2 * w + 1;
    float p0 = 0.f, p1 = 0.f;
    for (int d = lane; d < 768; d += 64) {
        float f = fs[d];
        p0 += f * wg[d * 8 + e0];
        p1 += f * wg[d * 8 + e1];
    }
    p0 = wred_sum(p0); p1 = wred_sum(p1);
    if (lane == 0) { lg[e0] = p0; lg[e1] = p1; }
    __syncthreads();
    if (tid == 0) {
        float b0 = -1e30f, b1 = -1e30f;
        int i0 = 0, i1 = 0;
        for (int e = 0; e < 8; e++) {     // strict > keeps first occurrence (jax tie-break)
            float le = lg[e];
            if (le > b0) { b1 = b0; i1 = i0; b0 = le; i0 = e; }
            else if (le > b1) { b1 = le; i1 = e; }
        }
        float ex = expf(b1 - b0);
        float den = 1.f + ex;
        idx[t] = make_int2(i0, i1);
        gate[t] = make_float2(1.f / den, ex / den);
        atomicAdd(&cnt[i0], 1);
        atomicAdd(&cnt[i1], 1);
    }
}

// ---------------- routing ----------------
__global__ void offsets_kernel(const int* __restrict__ cnt, int* __restrict__ asg) {
    if (threadIdx.x == 0 && blockIdx.x == 0) {
        int acc = 0;
        asg[0] = 0;
        for (int e = 0; e < 8; e++) { acc += (cnt[e] + 127) & ~127; asg[e + 1] = acc; }
    }
}

__global__ __launch_bounds__(256) void scatter_kernel(const int2* __restrict__ idx,
        const int* __restrict__ asg, int* __restrict__ cursor,
        int* __restrict__ list, int* __restrict__ pos) {
    int t = blockIdx.x * 256 + threadIdx.x;
    if (t >= T_TOK) return;
    int2 id = idx[t];
    int p0 = asg[id.x] + atomicAdd(&cursor[id.x], 1);
    list[p0] = t * 2;
    pos[t * 2] = p0;
    int p1 = asg[id.y] + atomicAdd(&cursor[id.y], 1);
    list[p1] = t * 2 + 1;
    pos[t * 2 + 1] = p1;
}

// ---------------- final: out = x1 + g0*(y0[p0]+y1[p0]) + g1*(y0[p1]+y1[p1])  (f32 out) ----------------
__global__ __launch_bounds__(256) void final_kernel(const float* __restrict__ x1,
        const float* __restrict__ yp0, const float* __restrict__ yp1, const int* __restrict__ pos,
        const float2* __restrict__ gate, float* __restrict__ out) {
    int t = blockIdx.x, tid = threadIdx.x;
    float2 g = gate[t];
    int p0 = pos[t * 2], p1 = pos[t * 2 + 1];
#pragma unroll
    for (int i = 0; i < 3; i++) {
        int d = tid + i * 256;
        float y0 = yp0[(size_t)p0 * 768 + d] + yp1[(size_t)p0 * 768 + d];
        float y1 = yp0[(size_t)p1 * 768 + d] + yp1[(size_t)p1 * 768 + d];
        out[(size_t)t * 768 + d] = x1[(size_t)t * 768 + d] + g.x * y0 + g.y * y1;
    }
}

extern "C" void kernel_launch(void* const* d_in, const int* in_sizes, int n_in,
                              void* d_out, int out_size, void* d_ws, size_t ws_size,
                              hipStream_t stream) {
    const float* x      = (const float*)d_in[0];
    const float* ln1_g  = (const float*)d_in[1];
    const float* ln1_b  = (const float*)d_in[2];
    const float* qkv_w  = (const float*)d_in[3];
    const float* qkv_b  = (const float*)d_in[4];
    const float* proj_w = (const float*)d_in[5];
    const float* proj_b = (const float*)d_in[6];
    const float* ln2_g  = (const float*)d_in[7];
    const float* ln2_b  = (const float*)d_in[8];
    const float* w_gate = (const float*)d_in[9];
    const float* w1     = (const float*)d_in[10];
    const float* b1     = (const float*)d_in[11];
    const float* w2     = (const float*)d_in[12];
    const float* b2     = (const float*)d_in[13];

    char* ws = (char*)d_ws;
    size_t off = 0;
    auto alloc = [&](size_t bytes) { size_t cur = off; off = (off + bytes + 255) & ~(size_t)255; return cur; };
    // region0: h_hi|h_lo|qkv_hi|qkv_lo|o_hi|o_lo (dead before MoE2) — reused as ypair0 (22.8MB <= 48.4MB)
    u16*    h_hi   = (u16*)   (ws + alloc((size_t)T_TOK * 768 * 2));
    u16*    h_lo   = (u16*)   (ws + alloc((size_t)T_TOK * 768 * 2));
    u16*    qkv_hi = (u16*)   (ws + alloc((size_t)T_TOK * 2304 * 2));
    u16*    qkv_lo = (u16*)   (ws + alloc((size_t)T_TOK * 2304 * 2));
    u16*    o_hi   = (u16*)   (ws + alloc((size_t)T_TOK * 768 * 2));
    u16*    o_lo   = (u16*)   (ws + alloc((size_t)T_TOK * 768 * 2));
    float*  ypair0 = (float*) ws;   // 7424*768*4 = 22.8MB <= region0
    float*  x1     = (float*) (ws + alloc((size_t)T_TOK * 768 * 4));
    u16*    flat   = (u16*)   (ws + alloc((size_t)T_TOK * 768 * 2));
    int2*   idx    = (int2*)  (ws + alloc((size_t)T_TOK * 8));
    float2* gate   = (float2*)(ws + alloc((size_t)T_TOK * 8));
    int*    cnt    = (int*)   (ws + alloc(64));     // cnt[8] + cursor[8]
    int*    cursor = cnt + 8;
    int*    asg    = (int*)   (ws + alloc(64));     // aligned_start[9]
    int*    list   = (int*)   (ws + alloc((size_t)LISTN * 4));
    int*    pos    = (int*)   (ws + alloc((size_t)T_TOK * 2 * 4));
    u16*    hid    = (u16*)   (ws + alloc((size_t)LISTN * 3072 * 2));
    u16*    qkvt_h = (u16*)   (ws + alloc((size_t)2304 * 768 * 2));
    u16*    qkvt_l = (u16*)   (ws + alloc((size_t)2304 * 768 * 2));
    u16*    projt_h = (u16*)  (ws + alloc((size_t)768 * 768 * 2));
    u16*    projt_l = (u16*)  (ws + alloc((size_t)768 * 768 * 2));
    u16*    w1t    = (u16*)   (ws + alloc((size_t)8 * 3072 * 768 * 2));
    u16*    w2t    = (u16*)   (ws + alloc((size_t)8 * 768 * 3072 * 2));
    float*  ypair1 = (float*) w1t;  // w1t (37.7MB) dead after moe1; ypair1 needs 22.8MB

    hipMemsetAsync(cnt, 0, 64, stream);
    hipMemsetAsync(list, 0xFF, (size_t)LISTN * 4, stream);

    // weight prep (bf16, [n][k] layout; qkv/proj split hi/lo)
    transp_kernel<1><<<dim3(12, 36, 1), 256, 0, stream>>>(qkv_w, qkvt_h, qkvt_l, 768, 2304);
    transp_kernel<1><<<dim3(12, 12, 1), 256, 0, stream>>>(proj_w, projt_h, projt_l, 768, 768);
    transp_kernel<0><<<dim3(12, 48, 8), 256, 0, stream>>>(w1, w1t, nullptr, 768, 3072);
    transp_kernel<0><<<dim3(48, 12, 8), 256, 0, stream>>>(w2, w2t, nullptr, 3072, 768);

    ln1_kernel<<<T_TOK, 256, 0, stream>>>(x, ln1_g, ln1_b, h_hi, h_lo);
    gemm128<0><<<dim3(25, 18), 256, 0, stream>>>(h_hi, h_lo, qkvt_h, qkvt_l, qkv_b, qkv_hi,
                                                 qkv_lo, nullptr, nullptr, nullptr, T_TOK, 2304, 768);
    attn_mfma_kernel<<<dim3(4, 192), 256, 0, stream>>>(qkv_hi, qkv_lo, o_hi, o_lo);
    gemm128<1><<<dim3(25, 6), 256, 0, stream>>>(o_hi, o_lo, projt_h, projt_l, proj_b, x1,
                                                nullptr, x, nullptr, nullptr, T_TOK, 768, 768);
    ln2_gate_kernel<<<T_TOK, 256, 0, stream>>>(x1, ln2_g, ln2_b, w_gate, flat, idx, gate, cnt);
    offsets_kernel<<<1, 64, 0, stream>>>(cnt, asg);
    scatter_kernel<<<(T_TOK + 255) / 256, 256, 0, stream>>>(idx, asg, cursor, list, pos);
    gemm_moe1<<<dim3(MOE_MT, 12), 256, 0, stream>>>(flat, w1t, b1, hid, list, asg);
    gemm128<3><<<dim3(MOE_MT, 6, 2), 256, 0, stream>>>(hid, nullptr, w2t, nullptr, b2, ypair0,
                                                       ypair1, nullptr, list, asg, LISTN, 768, 3072);
    final_kernel<<<T_TOK, 256, 0, stream>>>(x1, ypair0, ypair1, pos, gate, (float*)d_out);
}

// Round 9
// 583.696 us; speedup vs baseline: 1.1202x; 1.0127x over previous
//
#include <hip/hip_runtime.h>
#include <math.h>
#include <stdint.h>

typedef unsigned short u16;
typedef unsigned int u32;
typedef float floatx4 __attribute__((ext_vector_type(4)));
typedef __bf16 bf16x8 __attribute__((ext_vector_type(8)));

#define T_TOK 3152      // B*L = 16*197
#define SEQ 197
#define NH 12
#define LISTN 7424      // 58 tiles * 128 (worst-case 128-aligned expert segments)
#define MOE_MT 58

__device__ __forceinline__ float bf2f(u16 u) { return __uint_as_float(((u32)u) << 16); }
__device__ __forceinline__ u16 f2bf(float f) {
    u32 u = __float_as_uint(f);
    u += 0x7FFFu + ((u >> 16) & 1u);   // RNE
    return (u16)(u >> 16);
}
__device__ __forceinline__ float wred_sum(float v) {
#pragma unroll
    for (int off = 32; off; off >>= 1) v += __shfl_xor(v, off);
    return v;
}

// fast exact-enough gelu: A&S 7.1.26 erf, |err| <= 1.5e-7 (abs) -> bf16-identical vs erff
__device__ __forceinline__ float gelu_fast(float v) {
    float x = fabsf(v) * 0.70710678118654752f;
    float t = __builtin_amdgcn_rcpf(fmaf(0.3275911f, x, 1.0f));
    float p = t * fmaf(t, fmaf(t, fmaf(t, fmaf(t, 1.061405429f, -1.453152027f),
                                       1.421413741f), -0.284496736f), 0.254829592f);
    float er = fmaf(-p, __expf(-x * x), 1.0f);   // erf(|x|)
    er = copysignf(er, v);
    return 0.5f * v * (1.0f + er);
}

// async global->LDS, 16B per lane; LDS dest must be wave-uniform base (+lane*16 implicit)
#define GLB_AS(p) ((const __attribute__((address_space(1))) void*)(uintptr_t)(p))
#define LDS_AS(p) ((__attribute__((address_space(3))) void*)(uintptr_t)(p))
__device__ __forceinline__ void gl_lds16(const u16* g, u16* l) {
    __builtin_amdgcn_global_load_lds(GLB_AS(g), LDS_AS(l), 16, 0, 0);
}

// ---------------- weight prep: in f32 [z][R][C] -> out bf16 [z][C][R] (opt split hi/lo) ----------------
template <int SPLIT>
__global__ __launch_bounds__(256) void transp_kernel(const float* __restrict__ in,
        u16* __restrict__ oh, u16* __restrict__ ol, int R, int C) {
    int r0 = blockIdx.x * 64, c0 = blockIdx.y * 64;
    size_t zo = (size_t)blockIdx.z * R * C;
    __shared__ float Lt[64][68];
    int tid = threadIdx.x;
    int rr = tid >> 2, cs = (tid & 3) * 16;
    const float* src = in + zo + (size_t)(r0 + rr) * C + c0 + cs;
#pragma unroll
    for (int i = 0; i < 4; i++) *(float4*)&Lt[rr][cs + i * 4] = *(const float4*)(src + i * 4);
    __syncthreads();
    int cw = tid >> 2, rs = (tid & 3) * 16;
    u16 hv[16], lv[16];
#pragma unroll
    for (int j = 0; j < 16; j++) {
        float v = Lt[rs + j][cw];
        u16 hb = f2bf(v);
        hv[j] = hb;
        if (SPLIT) lv[j] = f2bf(v - bf2f(hb));
    }
    u16* dst = oh + zo + (size_t)(c0 + cw) * R + r0 + rs;
    *(uint4*)dst = *(const uint4*)&hv[0];
    *(uint4*)(dst + 8) = *(const uint4*)&hv[8];
    if (SPLIT) {
        u16* dstl = ol + zo + (size_t)(c0 + cw) * R + r0 + rs;
        *(uint4*)dstl = *(const uint4*)&lv[0];
        *(uint4*)(dstl + 8) = *(const uint4*)&lv[8];
    }
}

// ---------------- LN1: h = LN(x)*g+b, split to bf16 hi/lo planes ----------------
__global__ __launch_bounds__(256) void ln1_kernel(const float* __restrict__ x,
        const float* __restrict__ g, const float* __restrict__ b,
        u16* __restrict__ h_hi, u16* __restrict__ h_lo) {
    int t = blockIdx.x, tid = threadIdx.x;
    int w = tid >> 6, lane = tid & 63;
    float v[3];
#pragma unroll
    for (int i = 0; i < 3; i++) v[i] = x[(size_t)t * 768 + tid + i * 256];
    float s = v[0] + v[1] + v[2];
    float q = v[0] * v[0] + v[1] * v[1] + v[2] * v[2];
    s = wred_sum(s); q = wred_sum(q);
    __shared__ float red[8];
    if (lane == 0) { red[w] = s; red[4 + w] = q; }
    __syncthreads();
    float st = red[0] + red[1] + red[2] + red[3];
    float qt = red[4] + red[5] + red[6] + red[7];
    float mean = st * (1.f / 768.f);
    float var = qt * (1.f / 768.f) - mean * mean;
    float rs = rsqrtf(var + 1e-5f);
#pragma unroll
    for (int i = 0; i < 3; i++) {
        int d = tid + i * 256;
        float hv = (v[i] - mean) * rs * g[d] + b[d];
        u16 hi = f2bf(hv);
        h_hi[(size_t)t * 768 + d] = hi;
        h_lo[(size_t)t * 768 + d] = f2bf(hv - bf2f(hi));
    }
}

// ---------------- unified 128x128 MFMA GEMM ----------------
// global_load_lds staging, XCD-partitioned bijective grid swizzle, B pre-transposed bf16 [n][k].
// SPLIT modes (0/1): 2-buffer counted-vmcnt single-barrier pipeline (loads in flight across barrier).
// MODE 2/3: TRIPLE-buffer counted-vmcnt pipeline (r4-proven 48KB config).
// MODE 0: qkv split -> bf16 hi/lo planes (Cv/Cv2). MODE 1: proj split + resid -> f32.
// MODE 2: moe1 gathered A, gelu -> bf16 (LDS-coalesced stores). MODE 3: moe2 dense A -> f32,
//         split-K; z=0 -> Cv, z=1 -> Cv2 (separate buffers).
template <int MODE>
__global__ __launch_bounds__(256) void gemm128(const u16* __restrict__ Ah,
        const u16* __restrict__ Al, const u16* __restrict__ Bh, const u16* __restrict__ Bl,
        const float* __restrict__ bias, void* __restrict__ Cv, void* __restrict__ Cv2,
        const float* __restrict__ resid,
        const int* __restrict__ list, const int* __restrict__ asg, int M, int N, int K) {
    constexpr bool SPLIT = (MODE <= 1);
    constexpr int GX = (MODE <= 1) ? 25 : MOE_MT;                    // m-tiles
    constexpr int GY = (MODE == 0) ? 18 : (MODE == 2) ? 24 : 6;      // n-tiles
    constexpr int GZ = (MODE == 3) ? 2 : 1;                          // split-K
    constexpr int G  = GX * GY * GZ;
    constexpr int NT = GY * GZ;
    constexpr int Q8 = G >> 3, R8 = G & 7;

    // dispatch index -> XCD-contiguous tile id (bijective, m204 form); HW round-robins d%8 over XCDs
    int d = blockIdx.x + GX * (blockIdx.y + GY * blockIdx.z);
    int j = d & 7, s = d >> 3;
    int v = (j < R8) ? (j * (Q8 + 1) + s) : (R8 * (Q8 + 1) + (j - R8) * Q8 + s);
    int mt = v / NT, nzr = v - mt * NT;
    int yt = nzr % GY, zt = nzr / GY;
    int m0 = mt * 128, n0 = yt * 128;

    const u16* Bph = Bh;
    const float* bp = bias;
    const u16* Bpl = Bl;
    if (MODE >= 2) {
        if (m0 >= asg[8]) return;
        int e = 0;
        while (m0 >= asg[e + 1]) ++e;    // uniform across block
        Bph = Bh + (size_t)e * N * K;
        bp = bias + (size_t)e * N;
    }
    int kbeg = 0, kend = K;
    if (MODE == 3) { int kh = K >> 1; kbeg = zt * kh; kend = kbeg + kh; }

    // LDS pool. SPLIT: 2 bufs x {Ah,Bh,Al,Bl} x 8KB = 64KB. MODE2/3: 3 bufs x {A,B} x 8KB = 48KB
    // (MODE2 epilogue reuses first 32KB as the 128x128 bf16 C-tile).
    __shared__ __align__(16) u16 SM[SPLIT ? 32768 : 24576];
    u16* Ash = SM;
    u16* Bsh = SM + (SPLIT ? 8192 : 12288);
    u16* Asl = SM + 16384;   // SPLIT only
    u16* Bsl = SM + 24576;   // SPLIT only

    int tid = threadIdx.x;
    int w = tid >> 6, lane = tid & 63, l15 = lane & 15, quad = lane >> 4;
    int wm = (w & 1) * 64, wn = (w >> 1) * 64;
    int lr = lane >> 2;
    // source granule swizzle: LDS slot (row=lane>>2, gpos=lane&3) holds logical granule
    // gpos ^ ((row>>1)&3); since (lane>>3)&3 == (tile_row>>1)&3 this is per-lane source math only.
    int lc = ((lane & 3) ^ ((lane >> 3) & 3)) * 8;

    const u16* ga[2]; const u16* gal[2];
    const u16* gb[2]; const u16* gbl[2];
    int ldro[2];
#pragma unroll
    for (int it = 0; it < 2; it++) {
        int arow = m0 + it * 64 + w * 16 + lr;
        if (MODE == 2) {
            int entry = list[arow];
            ga[it] = Ah + (size_t)(entry >= 0 ? (entry >> 1) : 0) * K + lc;  // invalid -> row0, store-guarded
        } else if (MODE == 3) {
            ga[it] = Ah + (size_t)arow * K + lc;   // padding rows finite poison; store-guarded
        } else {
            int rc = min(arow, M - 1);
            ga[it] = Ah + (size_t)rc * K + lc;
            gal[it] = Al + (size_t)rc * K + lc;
        }
        int brow = n0 + it * 64 + w * 16 + lr;
        gb[it] = Bph + (size_t)brow * K + lc;
        if (SPLIT) gbl[it] = Bpl + (size_t)brow * K + lc;
        ldro[it] = (it * 64 + w * 16) * 32;       // wave-uniform LDS chunk base (within a buffer)
    }

    // read addresses (loop-invariant): row-major [128][32] with XOR granule de-swizzle
    int ra[4], rb[4];
#pragma unroll
    for (int i = 0; i < 4; i++) {
        int r1 = wm + i * 16 + l15;
        ra[i] = r1 * 32 + (quad ^ ((r1 >> 1) & 3)) * 8;
        int r2 = wn + i * 16 + l15;
        rb[i] = r2 * 32 + (quad ^ ((r2 >> 1) & 3)) * 8;
    }

    floatx4 acc[4][4];
#pragma unroll
    for (int mi = 0; mi < 4; mi++)
#pragma unroll
        for (int ni = 0; ni < 4; ni++) acc[mi][ni] = (floatx4){0.f, 0.f, 0.f, 0.f};

    auto stage = [&](int buf, int k0) {
        int bo = buf * 4096;
#pragma unroll
        for (int it = 0; it < 2; it++) {
            gl_lds16(ga[it] + k0, &Ash[bo + ldro[it]]);
            gl_lds16(gb[it] + k0, &Bsh[bo + ldro[it]]);
            if constexpr (SPLIT) {
                gl_lds16(gal[it] + k0, &Asl[bo + ldro[it]]);
                gl_lds16(gbl[it] + k0, &Bsl[bo + ldro[it]]);
            }
        }
    };
    auto compute = [&](int buf) {
        int bo = buf * 4096;
        bf16x8 afh[4], bfh[4], afl[4], bfl[4];
#pragma unroll
        for (int i = 0; i < 4; i++) {
            afh[i] = *(const bf16x8*)&Ash[bo + ra[i]];
            bfh[i] = *(const bf16x8*)&Bsh[bo + rb[i]];
            if constexpr (SPLIT) {
                afl[i] = *(const bf16x8*)&Asl[bo + ra[i]];
                bfl[i] = *(const bf16x8*)&Bsl[bo + rb[i]];
            }
        }
        __builtin_amdgcn_s_setprio(1);
#pragma unroll
        for (int mi = 0; mi < 4; mi++)
#pragma unroll
            for (int ni = 0; ni < 4; ni++) {
                if constexpr (SPLIT) {
                    acc[mi][ni] = __builtin_amdgcn_mfma_f32_16x16x32_bf16(afl[mi], bfh[ni], acc[mi][ni], 0, 0, 0);
                    acc[mi][ni] = __builtin_amdgcn_mfma_f32_16x16x32_bf16(afh[mi], bfl[ni], acc[mi][ni], 0, 0, 0);
                }
                acc[mi][ni] = __builtin_amdgcn_mfma_f32_16x16x32_bf16(afh[mi], bfh[ni], acc[mi][ni], 0, 0, 0);
            }
        __builtin_amdgcn_s_setprio(0);
    };

    int nsteps = (kend - kbeg) >> 5;
    if constexpr (SPLIT) {
        // 2-buffer counted-vmcnt single-barrier pipeline: loads stay in flight across the barrier.
        stage(0, kbeg);
        stage(1, kbeg + 32);
        asm volatile("s_waitcnt vmcnt(8)" ::: "memory");   // buf0's 8 landed (buf1's 8 in flight)
        __builtin_amdgcn_s_barrier();
        for (int t = 0; t < nsteps; ++t) {
            compute(t & 1);
            asm volatile("s_waitcnt lgkmcnt(0)" ::: "memory");  // my reads of buf t done
            __builtin_amdgcn_s_barrier();                        // all waves done reading buf t
            if (t + 2 < nsteps) {
                stage(t & 1, kbeg + (t + 2) * 32);               // overwrite buf t for step t+2
                asm volatile("s_waitcnt vmcnt(8)" ::: "memory"); // buf t+1 landed; newest 8 in flight
            } else if (t + 1 < nsteps) {
                asm volatile("s_waitcnt vmcnt(0)" ::: "memory"); // drain for final step
            }
        }
    } else {
        // depth-3 counted-vmcnt pipeline (r4-proven); 4 gl_lds per stage per wave.
        stage(0, kbeg);
        stage(1, kbeg + 32);
        asm volatile("s_waitcnt vmcnt(4)" ::: "memory");   // buf0 landed (buf1 = 4 in flight)
        __builtin_amdgcn_s_barrier();
        int bufc = 0;
        for (int t = 0; t < nsteps; ++t) {
            int b2 = bufc + 2; if (b2 >= 3) b2 -= 3;
            if (t + 2 < nsteps) stage(b2, kbeg + (t + 2) * 32);   // overwrites buf(t-1): freed by prev barrier
            compute(bufc);
            if (t + 2 < nsteps) {
                asm volatile("s_waitcnt vmcnt(4) lgkmcnt(0)" ::: "memory");
            } else {
                asm volatile("s_waitcnt vmcnt(0) lgkmcnt(0)" ::: "memory");
            }
            __builtin_amdgcn_s_barrier();
            bufc = (bufc == 2) ? 0 : bufc + 1;
        }
    }

    if constexpr (MODE == 2) {
        // stage gelu(bf16) tile into SM[128][128] (col XOR-swizzled), then coalesced row stores
#pragma unroll
        for (int ni = 0; ni < 4; ni++) {
            int col = wn + ni * 16 + l15;
            float bb = bp[n0 + col];
#pragma unroll
            for (int mi = 0; mi < 4; mi++) {
#pragma unroll
                for (int r = 0; r < 4; r++) {
                    int row = wm + mi * 16 + quad * 4 + r;
                    float gv = gelu_fast(acc[mi][ni][r] + bb);
                    SM[row * 128 + (col ^ ((row & 7) << 3))] = f2bf(gv);
                }
            }
        }
        __syncthreads();
        int rr = tid >> 1, half = (tid & 1) * 64;
        int grow = m0 + rr;
        if (list[grow] >= 0) {
            u16* dst = (u16*)Cv + (size_t)grow * N + n0 + half;
            int xr = (rr & 7) << 3;
#pragma unroll
            for (int gch = 0; gch < 8; gch++) {
                int cb = (half + gch * 8) ^ xr;
                *(uint4*)(dst + gch * 8) = *(const uint4*)&SM[rr * 128 + cb];
            }
        }
        return;
    }

    float* Cf = (float*)Cv;
    if (MODE == 3 && zt != 0) Cf = (float*)Cv2;
#pragma unroll
    for (int ni = 0; ni < 4; ni++) {
        int col = n0 + wn + ni * 16 + l15;
        float bb = bp[col];
        if (MODE == 3 && zt != 0) bb = 0.f;   // bias added once (z=0 half)
#pragma unroll
        for (int mi = 0; mi < 4; mi++) {
#pragma unroll
            for (int r = 0; r < 4; r++) {
                int row = m0 + wm + mi * 16 + quad * 4 + r;
                float v2 = acc[mi][ni][r] + bb;
                if (MODE == 0) {
                    if (row < M) {
                        u16 hb = f2bf(v2);
                        ((u16*)Cv)[(size_t)row * N + col] = hb;
                        ((u16*)Cv2)[(size_t)row * N + col] = f2bf(v2 - bf2f(hb));
                    }
                } else if (MODE == 1) {
                    if (row < M) Cf[(size_t)row * N + col] = v2 + resid[(size_t)row * N + col];
                } else {
                    if (list[row] >= 0) Cf[(size_t)row * N + col] = v2;
                }
            }
        }
    }
}

// ---------------- MFMA attention: bf16 hi/lo qkv planes; block = (b, h, 64-q-tile), 4 waves ----------------
__global__ __launch_bounds__(256) void attn_mfma_kernel(const u16* __restrict__ qph,
        const u16* __restrict__ qpl, u16* __restrict__ ohi, u16* __restrict__ olo) {
    // bijective XCD swizzle over 768 blocks: XCD j gets 24 consecutive (b,h) with all 4 q-tiles
    int d = blockIdx.x + 4 * blockIdx.y;
    int j = d & 7, sdx = d >> 3;
    int v = j * 96 + sdx;
    int qbase = (v & 3) * 64;
    int by = v >> 2;
    int b = by / NH, h = by % NH;
    int tid = threadIdx.x;
    int w = tid >> 6, lane = tid & 63, l15 = lane & 15, quad = lane >> 4;

    __shared__ u16 Qh[64 * 64], Ql[64 * 64];
    __shared__ u16 Sh[64 * 64], Sl[64 * 64];   // K tile, then V^T tile
    __shared__ u16 Ph[64 * 72], Pl[64 * 72];

    int grow8 = lane >> 3;                     // row within 8-row gl_lds group
    int gsrc = ((lane & 7) ^ grow8) * 8;       // swizzled source granule (u16 offset)
    int srow = tid >> 2;                       // V^T: key index
    int scol = (tid & 3) * 16;                 // V^T: d base

    // --- stage Q (gl_lds, swizzled) ---
#pragma unroll
    for (int it = 0; it < 2; it++) {
        int r = qbase + w * 16 + it * 8 + grow8;
        int rc = min(r, SEQ - 1);
        size_t so = (size_t)(b * SEQ + rc) * 2304 + h * 64 + gsrc;
        gl_lds16(qph + so, &Qh[(w * 16 + it * 8) * 64]);
        gl_lds16(qpl + so, &Ql[(w * 16 + it * 8) * 64]);
    }
    __syncthreads();
    bf16x8 aqh[2], aql[2];
#pragma unroll
    for (int s2 = 0; s2 < 2; s2++) {
        int row = w * 16 + l15;
        int ad = row * 64 + (((s2 * 4 + quad) ^ (row & 7))) * 8;
        aqh[s2] = *(const bf16x8*)&Qh[ad];
        aql[s2] = *(const bf16x8*)&Ql[ad];
    }

    floatx4 sc[16];
#pragma unroll
    for (int f = 0; f < 16; f++) sc[f] = (floatx4){0.f, 0.f, 0.f, 0.f};

    for (int t = 0; t < 4; t++) {
#pragma unroll
        for (int it = 0; it < 2; it++) {
            int r = t * 64 + w * 16 + it * 8 + grow8;
            int rc = min(r, SEQ - 1);
            size_t so = (size_t)(b * SEQ + rc) * 2304 + 768 + h * 64 + gsrc;
            gl_lds16(qph + so, &Sh[(w * 16 + it * 8) * 64]);
            gl_lds16(qpl + so, &Sl[(w * 16 + it * 8) * 64]);
        }
        __syncthreads();
#pragma unroll
        for (int s = 0; s < 4; s++) {
            int row = s * 16 + l15;
#pragma unroll
            for (int s2 = 0; s2 < 2; s2++) {
                int ad = row * 64 + (((s2 * 4 + quad) ^ (row & 7))) * 8;
                bf16x8 bkh = *(const bf16x8*)&Sh[ad];
                bf16x8 bkl = *(const bf16x8*)&Sl[ad];
                sc[t * 4 + s] = __builtin_amdgcn_mfma_f32_16x16x32_bf16(aql[s2], bkh, sc[t * 4 + s], 0, 0, 0);
                sc[t * 4 + s] = __builtin_amdgcn_mfma_f32_16x16x32_bf16(aqh[s2], bkl, sc[t * 4 + s], 0, 0, 0);
                sc[t * 4 + s] = __builtin_amdgcn_mfma_f32_16x16x32_bf16(aqh[s2], bkh, sc[t * 4 + s], 0, 0, 0);
            }
        }
        __syncthreads();
    }

    float m[4] = {-1e30f, -1e30f, -1e30f, -1e30f};
#pragma unroll
    for (int f = 0; f < 16; f++) {
        int key = (f >> 2) * 64 + (f & 3) * 16 + l15;
        bool valid = key < SEQ;
#pragma unroll
        for (int r = 0; r < 4; r++) {
            float s = valid ? sc[f][r] * 0.125f : -1e30f;
            sc[f][r] = s;
            m[r] = fmaxf(m[r], s);
        }
    }
#pragma unroll
    for (int r = 0; r < 4; r++) {
#pragma unroll
        for (int off = 1; off < 16; off <<= 1) m[r] = fmaxf(m[r], __shfl_xor(m[r], off));
    }
    float sum[4] = {0.f, 0.f, 0.f, 0.f};
#pragma unroll
    for (int f = 0; f < 16; f++) {
#pragma unroll
        for (int r = 0; r < 4; r++) {
            float p = expf(sc[f][r] - m[r]);
            sc[f][r] = p;
            sum[r] += p;
        }
    }
    float inv[4];
#pragma unroll
    for (int r = 0; r < 4; r++) {
#pragma unroll
        for (int off = 1; off < 16; off <<= 1) sum[r] += __shfl_xor(sum[r], off);
        inv[r] = 1.f / sum[r];
    }

    floatx4 oacc[4];
#pragma unroll
    for (int sd = 0; sd < 4; sd++) oacc[sd] = (floatx4){0.f, 0.f, 0.f, 0.f};

    for (int t = 0; t < 4; t++) {
#pragma unroll
        for (int s = 0; s < 4; s++) {
#pragma unroll
            for (int r = 0; r < 4; r++) {
                float p = sc[t * 4 + s][r];
                u16 hb = f2bf(p);
                int row = w * 16 + quad * 4 + r;
                Ph[row * 72 + s * 16 + l15] = hb;
                Pl[row * 72 + s * 16 + l15] = f2bf(p - bf2f(hb));
            }
        }
        {
            // V^T staging from bf16 planes (u16-only), granule-swizzled for conflict-free reads
            int key = t * 64 + srow;
            int kc = min(key, SEQ - 1);   // garbage rows hit P==0 (masked scores), finite => safe
            size_t so = (size_t)(b * SEQ + kc) * 2304 + 1536 + h * 64 + scol;
            u16 hv[16], lv[16];
            *(uint4*)&hv[0] = *(const uint4*)(qph + so);
            *(uint4*)&hv[8] = *(const uint4*)(qph + so + 8);
            *(uint4*)&lv[0] = *(const uint4*)(qpl + so);
            *(uint4*)&lv[8] = *(const uint4*)(qpl + so + 8);
            int kg = srow >> 3, kw = srow & 7;
#pragma unroll
            for (int i = 0; i < 16; i++) {
                int dcol = scol + i;
                int idx = dcol * 64 + ((kg ^ (dcol & 7)) * 8) + kw;
                Sh[idx] = hv[i];
                Sl[idx] = lv[i];
            }
        }
        __syncthreads();
#pragma unroll
        for (int s2 = 0; s2 < 2; s2++) {
            bf16x8 aph = *(const bf16x8*)&Ph[(w * 16 + l15) * 72 + s2 * 32 + quad * 8];
            bf16x8 apl = *(const bf16x8*)&Pl[(w * 16 + l15) * 72 + s2 * 32 + quad * 8];
#pragma unroll
            for (int sd = 0; sd < 4; sd++) {
                int row = sd * 16 + l15;
                int ad = row * 64 + (((s2 * 4 + quad) ^ (row & 7))) * 8;
                bf16x8 bvh = *(const bf16x8*)&Sh[ad];
                bf16x8 bvl = *(const bf16x8*)&Sl[ad];
                oacc[sd] = __builtin_amdgcn_mfma_f32_16x16x32_bf16(apl, bvh, oacc[sd], 0, 0, 0);
                oacc[sd] = __builtin_amdgcn_mfma_f32_16x16x32_bf16(aph, bvl, oacc[sd], 0, 0, 0);
                oacc[sd] = __builtin_amdgcn_mfma_f32_16x16x32_bf16(aph, bvh, oacc[sd], 0, 0, 0);
            }
        }
        __syncthreads();
    }

#pragma unroll
    for (int sd = 0; sd < 4; sd++) {
#pragma unroll
        for (int r = 0; r < 4; r++) {
            int q = qbase + w * 16 + quad * 4 + r;
            if (q < SEQ) {
                float val = oacc[sd][r] * inv[r];
                u16 hb = f2bf(val);
                size_t o = ((size_t)(b * SEQ + q)) * 768 + h * 64 + sd * 16 + l15;
                ohi[o] = hb;
                olo[o] = f2bf(val - bf2f(hb));
            }
        }
    }
}

// ---------------- LN2 + gate (top-2 of 8) + fused histogram ----------------
__global__ __launch_bounds__(256) void ln2_gate_kernel(const float* __restrict__ x1,
        const float* __restrict__ g, const float* __restrict__ b, const float* __restrict__ wg,
        u16* __restrict__ flat, int2* __restrict__ idx, float2* __restrict__ gate,
        int* __restrict__ cnt) {
    int t = blockIdx.x, tid = threadIdx.x;
    int w = tid >> 6, lane = tid & 63;
    float v[3];
#pragma unroll
    for (int i = 0; i < 3; i++) v[i] = x1[(size_t)t * 768 + tid + i * 256];
    float s = v[0] + v[1] + v[2];
    float q = v[0] * v[0] + v[1] * v[1] + v[2] * v[2];
    s = wred_sum(s); q = wred_sum(q);
    __shared__ float red[8];
    __shared__ float fs[768];
    __shared__ float lg[8];
    if (lane == 0) { red[w] = s; red[4 + w] = q; }
    __syncthreads();
    float st = red[0] + red[1] + red[2] + red[3];
    float qt = red[4] + red[5] + red[6] + red[7];
    float mean = st * (1.f / 768.f);
    float var = qt * (1.f / 768.f) - mean * mean;
    float rs = rsqrtf(var + 1e-5f);
#pragma unroll
    for (int i = 0; i < 3; i++) {
        int d = tid + i * 256;
        float f = (v[i] - mean) * rs * g[d] + b[d];
        flat[(size_t)t * 768 + d] = f2bf(f);
        fs[d] = f;
    }
    __syncthreads();
    int e0 = 2 * w, e1 = 2 * w + 1;
    float p0 = 0.f, p1 = 0.f;
    for (int d = lane; d < 768; d += 64) {
        float f = fs[d];
        p0 += f * wg[d * 8 + e0];
        p1 += f * wg[d * 8 + e1];
    }
    p0 = wred_sum(p0); p1 = wred_sum(p1);
    if (lane == 0) { lg[e0] = p0; lg[e1] = p1; }
    __syncthreads();
    if (tid == 0) {
        float b0 = -1e30f, b1 = -1e30f;
        int i0 = 0, i1 = 0;
        for (int e = 0; e < 8; e++) {     // strict > keeps first occurrence (jax tie-break)
            float le = lg[e];
            if (le > b0) { b1 = b0; i1 = i0; b0 = le; i0 = e; }
            else if (le > b1) { b1 = le; i1 = e; }
        }
        float ex = expf(b1 - b0);
        float den = 1.f + ex;
        idx[t] = make_int2(i0, i1);
        gate[t] = make_float2(1.f / den, ex / den);
        atomicAdd(&cnt[i0], 1);
        atomicAdd(&cnt[i1], 1);
    }
}

// ---------------- routing ----------------
__global__ void offsets_kernel(const int* __restrict__ cnt, int* __restrict__ asg) {
    if (threadIdx.x == 0 && blockIdx.x == 0) {
        int acc = 0;
        asg[0] = 0;
        for (int e = 0; e < 8; e++) { acc += (cnt[e] + 127) & ~127; asg[e + 1] = acc; }
    }
}

__global__ __launch_bounds__(256) void scatter_kernel(const int2* __restrict__ idx,
        const int* __restrict__ asg, int* __restrict__ cursor,
        int* __restrict__ list, int* __restrict__ pos) {
    int t = blockIdx.x * 256 + threadIdx.x;
    if (t >= T_TOK) return;
    int2 id = idx[t];
    int p0 = asg[id.x] + atomicAdd(&cursor[id.x], 1);
    list[p0] = t * 2;
    pos[t * 2] = p0;
    int p1 = asg[id.y] + atomicAdd(&cursor[id.y], 1);
    list[p1] = t * 2 + 1;
    pos[t * 2 + 1] = p1;
}

// ---------------- final: out = x1 + g0*(y0[p0]+y1[p0]) + g1*(y0[p1]+y1[p1])  (f32 out) ----------------
__global__ __launch_bounds__(256) void final_kernel(const float* __restrict__ x1,
        const float* __restrict__ yp0, const float* __restrict__ yp1, const int* __restrict__ pos,
        const float2* __restrict__ gate, float* __restrict__ out) {
    int t = blockIdx.x, tid = threadIdx.x;
    float2 g = gate[t];
    int p0 = pos[t * 2], p1 = pos[t * 2 + 1];
#pragma unroll
    for (int i = 0; i < 3; i++) {
        int d = tid + i * 256;
        float y0 = yp0[(size_t)p0 * 768 + d] + yp1[(size_t)p0 * 768 + d];
        float y1 = yp0[(size_t)p1 * 768 + d] + yp1[(size_t)p1 * 768 + d];
        out[(size_t)t * 768 + d] = x1[(size_t)t * 768 + d] + g.x * y0 + g.y * y1;
    }
}

extern "C" void kernel_launch(void* const* d_in, const int* in_sizes, int n_in,
                              void* d_out, int out_size, void* d_ws, size_t ws_size,
                              hipStream_t stream) {
    const float* x      = (const float*)d_in[0];
    const float* ln1_g  = (const float*)d_in[1];
    const float* ln1_b  = (const float*)d_in[2];
    const float* qkv_w  = (const float*)d_in[3];
    const float* qkv_b  = (const float*)d_in[4];
    const float* proj_w = (const float*)d_in[5];
    const float* proj_b = (const float*)d_in[6];
    const float* ln2_g  = (const float*)d_in[7];
    const float* ln2_b  = (const float*)d_in[8];
    const float* w_gate = (const float*)d_in[9];
    const float* w1     = (const float*)d_in[10];
    const float* b1     = (const float*)d_in[11];
    const float* w2     = (const float*)d_in[12];
    const float* b2     = (const float*)d_in[13];

    char* ws = (char*)d_ws;
    size_t off = 0;
    auto alloc = [&](size_t bytes) { size_t cur = off; off = (off + bytes + 255) & ~(size_t)255; return cur; };
    // region0: h_hi|h_lo|qkv_hi|qkv_lo|o_hi|o_lo (dead before MoE2) — reused as ypair0 (22.8MB <= 48.4MB)
    u16*    h_hi   = (u16*)   (ws + alloc((size_t)T_TOK * 768 * 2));
    u16*    h_lo   = (u16*)   (ws + alloc((size_t)T_TOK * 768 * 2));
    u16*    qkv_hi = (u16*)   (ws + alloc((size_t)T_TOK * 2304 * 2));
    u16*    qkv_lo = (u16*)   (ws + alloc((size_t)T_TOK * 2304 * 2));
    u16*    o_hi   = (u16*)   (ws + alloc((size_t)T_TOK * 768 * 2));
    u16*    o_lo   = (u16*)   (ws + alloc((size_t)T_TOK * 768 * 2));
    float*  ypair0 = (float*) ws;   // 7424*768*4 = 22.8MB <= region0
    float*  x1     = (float*) (ws + alloc((size_t)T_TOK * 768 * 4));
    u16*    flat   = (u16*)   (ws + alloc((size_t)T_TOK * 768 * 2));
    int2*   idx    = (int2*)  (ws + alloc((size_t)T_TOK * 8));
    float2* gate   = (float2*)(ws + alloc((size_t)T_TOK * 8));
    int*    cnt    = (int*)   (ws + alloc(64));     // cnt[8] + cursor[8]
    int*    cursor = cnt + 8;
    int*    asg    = (int*)   (ws + alloc(64));     // aligned_start[9]
    int*    list   = (int*)   (ws + alloc((size_t)LISTN * 4));
    int*    pos    = (int*)   (ws + alloc((size_t)T_TOK * 2 * 4));
    u16*    hid    = (u16*)   (ws + alloc((size_t)LISTN * 3072 * 2));
    u16*    qkvt_h = (u16*)   (ws + alloc((size_t)2304 * 768 * 2));
    u16*    qkvt_l = (u16*)   (ws + alloc((size_t)2304 * 768 * 2));
    u16*    projt_h = (u16*)  (ws + alloc((size_t)768 * 768 * 2));
    u16*    projt_l = (u16*)  (ws + alloc((size_t)768 * 768 * 2));
    u16*    w1t    = (u16*)   (ws + alloc((size_t)8 * 3072 * 768 * 2));
    u16*    w2t    = (u16*)   (ws + alloc((size_t)8 * 768 * 3072 * 2));
    float*  ypair1 = (float*) w1t;  // w1t (37.7MB) dead after moe1; ypair1 needs 22.8MB

    hipMemsetAsync(cnt, 0, 64, stream);
    hipMemsetAsync(list, 0xFF, (size_t)LISTN * 4, stream);

    // weight prep (bf16, [n][k] layout; qkv/proj split hi/lo)
    transp_kernel<1><<<dim3(12, 36, 1), 256, 0, stream>>>(qkv_w, qkvt_h, qkvt_l, 768, 2304);
    transp_kernel<1><<<dim3(12, 12, 1), 256, 0, stream>>>(proj_w, projt_h, projt_l, 768, 768);
    transp_kernel<0><<<dim3(12, 48, 8), 256, 0, stream>>>(w1, w1t, nullptr, 768, 3072);
    transp_kernel<0><<<dim3(48, 12, 8), 256, 0, stream>>>(w2, w2t, nullptr, 3072, 768);

    ln1_kernel<<<T_TOK, 256, 0, stream>>>(x, ln1_g, ln1_b, h_hi, h_lo);
    gemm128<0><<<dim3(25, 18), 256, 0, stream>>>(h_hi, h_lo, qkvt_h, qkvt_l, qkv_b, qkv_hi,
                                                 qkv_lo, nullptr, nullptr, nullptr, T_TOK, 2304, 768);
    attn_mfma_kernel<<<dim3(4, 192), 256, 0, stream>>>(qkv_hi, qkv_lo, o_hi, o_lo);
    gemm128<1><<<dim3(25, 6), 256, 0, stream>>>(o_hi, o_lo, projt_h, projt_l, proj_b, x1,
                                                nullptr, x, nullptr, nullptr, T_TOK, 768, 768);
    ln2_gate_kernel<<<T_TOK, 256, 0, stream>>>(x1, ln2_g, ln2_b, w_gate, flat, idx, gate, cnt);
    offsets_kernel<<<1, 64, 0, stream>>>(cnt, asg);
    scatter_kernel<<<(T_TOK + 255) / 256, 256, 0, stream>>>(idx, asg, cursor, list, pos);
    gemm128<2><<<dim3(MOE_MT, 24), 256, 0, stream>>>(flat, nullptr, w1t, nullptr, b1, hid,
                                                     nullptr, nullptr, list, asg, LISTN, 3072, 768);
    gemm128<3><<<dim3(MOE_MT, 6, 2), 256, 0, stream>>>(hid, nullptr, w2t, nullptr, b2, ypair0,
                                                       ypair1, nullptr, list, asg, LISTN, 768, 3072);
    final_kernel<<<T_TOK, 256, 0, stream>>>(x1, ypair0, ypair1, pos, gate, (float*)d_out);
}

// Round 10
// 500.782 us; speedup vs baseline: 1.3057x; 1.1656x over previous
//
#include <hip/hip_runtime.h>
#include <math.h>
#include <stdint.h>

typedef unsigned short u16;
typedef unsigned int u32;
typedef float floatx4 __attribute__((ext_vector_type(4)));
typedef __bf16 bf16x8 __attribute__((ext_vector_type(8)));

#define T_TOK 3152      // B*L = 16*197
#define SEQ 197
#define NH 12
#define LISTN 7424      // 58 tiles * 128 (worst-case 128-aligned expert segments)
#define MOE_MT 58

__device__ __forceinline__ float bf2f(u16 u) { return __uint_as_float(((u32)u) << 16); }
__device__ __forceinline__ u16 f2bf(float f) {
    u32 u = __float_as_uint(f);
    u += 0x7FFFu + ((u >> 16) & 1u);   // RNE
    return (u16)(u >> 16);
}
__device__ __forceinline__ float wred_sum(float v) {
#pragma unroll
    for (int off = 32; off; off >>= 1) v += __shfl_xor(v, off);
    return v;
}
__device__ __forceinline__ int wred_sum_i(int v) {
#pragma unroll
    for (int off = 32; off; off >>= 1) v += __shfl_xor(v, off);
    return v;
}

// fast exact-enough gelu: A&S 7.1.26 erf, |err| <= 1.5e-7 (abs) -> bf16-identical vs erff
__device__ __forceinline__ float gelu_fast(float v) {
    float x = fabsf(v) * 0.70710678118654752f;
    float t = __builtin_amdgcn_rcpf(fmaf(0.3275911f, x, 1.0f));
    float p = t * fmaf(t, fmaf(t, fmaf(t, fmaf(t, 1.061405429f, -1.453152027f),
                                       1.421413741f), -0.284496736f), 0.254829592f);
    float er = fmaf(-p, __expf(-x * x), 1.0f);   // erf(|x|)
    er = copysignf(er, v);
    return 0.5f * v * (1.0f + er);
}

// async global->LDS, 16B per lane; LDS dest must be wave-uniform base (+lane*16 implicit)
#define GLB_AS(p) ((const __attribute__((address_space(1))) void*)(uintptr_t)(p))
#define LDS_AS(p) ((__attribute__((address_space(3))) void*)(uintptr_t)(p))
__device__ __forceinline__ void gl_lds16(const u16* g, u16* l) {
    __builtin_amdgcn_global_load_lds(GLB_AS(g), LDS_AS(l), 16, 0, 0);
}

// ---------------- weight prep: in f32 [z][R][C] -> out bf16 [z][C][R] (opt split hi/lo) ----------------
template <int SPLIT>
__global__ __launch_bounds__(256) void transp_kernel(const float* __restrict__ in,
        u16* __restrict__ oh, u16* __restrict__ ol, int R, int C) {
    int r0 = blockIdx.x * 64, c0 = blockIdx.y * 64;
    size_t zo = (size_t)blockIdx.z * R * C;
    __shared__ float Lt[64][68];
    int tid = threadIdx.x;
    int rr = tid >> 2, cs = (tid & 3) * 16;
    const float* src = in + zo + (size_t)(r0 + rr) * C + c0 + cs;
#pragma unroll
    for (int i = 0; i < 4; i++) *(float4*)&Lt[rr][cs + i * 4] = *(const float4*)(src + i * 4);
    __syncthreads();
    int cw = tid >> 2, rs = (tid & 3) * 16;
    u16 hv[16], lv[16];
#pragma unroll
    for (int j = 0; j < 16; j++) {
        float v = Lt[rs + j][cw];
        u16 hb = f2bf(v);
        hv[j] = hb;
        if (SPLIT) lv[j] = f2bf(v - bf2f(hb));
    }
    u16* dst = oh + zo + (size_t)(c0 + cw) * R + r0 + rs;
    *(uint4*)dst = *(const uint4*)&hv[0];
    *(uint4*)(dst + 8) = *(const uint4*)&hv[8];
    if (SPLIT) {
        u16* dstl = ol + zo + (size_t)(c0 + cw) * R + r0 + rs;
        *(uint4*)dstl = *(const uint4*)&lv[0];
        *(uint4*)(dstl + 8) = *(const uint4*)&lv[8];
    }
}

// ---------------- LN1: h = LN(x)*g+b, split to bf16 hi/lo planes ----------------
__global__ __launch_bounds__(256) void ln1_kernel(const float* __restrict__ x,
        const float* __restrict__ g, const float* __restrict__ b,
        u16* __restrict__ h_hi, u16* __restrict__ h_lo) {
    int t = blockIdx.x, tid = threadIdx.x;
    int w = tid >> 6, lane = tid & 63;
    float v[3];
#pragma unroll
    for (int i = 0; i < 3; i++) v[i] = x[(size_t)t * 768 + tid + i * 256];
    float s = v[0] + v[1] + v[2];
    float q = v[0] * v[0] + v[1] * v[1] + v[2] * v[2];
    s = wred_sum(s); q = wred_sum(q);
    __shared__ float red[8];
    if (lane == 0) { red[w] = s; red[4 + w] = q; }
    __syncthreads();
    float st = red[0] + red[1] + red[2] + red[3];
    float qt = red[4] + red[5] + red[6] + red[7];
    float mean = st * (1.f / 768.f);
    float var = qt * (1.f / 768.f) - mean * mean;
    float rs = rsqrtf(var + 1e-5f);
#pragma unroll
    for (int i = 0; i < 3; i++) {
        int d = tid + i * 256;
        float hv = (v[i] - mean) * rs * g[d] + b[d];
        u16 hi = f2bf(hv);
        h_hi[(size_t)t * 768 + d] = hi;
        h_lo[(size_t)t * 768 + d] = f2bf(hv - bf2f(hi));
    }
}

// ---------------- unified 128x128 MFMA GEMM ----------------
// global_load_lds staging, XCD-partitioned bijective grid swizzle, B pre-transposed bf16 [n][k].
// SPLIT modes (0/1): 2-buffer counted-vmcnt single-barrier pipeline (loads in flight across barrier).
// MODE 2/3: TRIPLE-buffer counted-vmcnt pipeline (r4-proven 48KB config).
// MODE 0: qkv split -> bf16 hi/lo planes (Cv/Cv2). MODE 1: proj split + resid -> f32.
// MODE 2: moe1 gathered A, gelu -> bf16 (LDS-coalesced stores). MODE 3: moe2 dense A -> f32,
//         split-K; z=0 -> Cv, z=1 -> Cv2 (separate buffers).
template <int MODE>
__global__ __launch_bounds__(256) void gemm128(const u16* __restrict__ Ah,
        const u16* __restrict__ Al, const u16* __restrict__ Bh, const u16* __restrict__ Bl,
        const float* __restrict__ bias, void* __restrict__ Cv, void* __restrict__ Cv2,
        const float* __restrict__ resid,
        const int* __restrict__ list, const int* __restrict__ asg, int M, int N, int K) {
    constexpr bool SPLIT = (MODE <= 1);
    constexpr int GX = (MODE <= 1) ? 25 : MOE_MT;                    // m-tiles
    constexpr int GY = (MODE == 0) ? 18 : (MODE == 2) ? 24 : 6;      // n-tiles
    constexpr int GZ = (MODE == 3) ? 2 : 1;                          // split-K
    constexpr int G  = GX * GY * GZ;
    constexpr int NT = GY * GZ;
    constexpr int Q8 = G >> 3, R8 = G & 7;

    // dispatch index -> XCD-contiguous tile id (bijective, m204 form); HW round-robins d%8 over XCDs
    int d = blockIdx.x + GX * (blockIdx.y + GY * blockIdx.z);
    int j = d & 7, s = d >> 3;
    int v = (j < R8) ? (j * (Q8 + 1) + s) : (R8 * (Q8 + 1) + (j - R8) * Q8 + s);
    int mt = v / NT, nzr = v - mt * NT;
    int yt = nzr % GY, zt = nzr / GY;
    int m0 = mt * 128, n0 = yt * 128;

    const u16* Bph = Bh;
    const float* bp = bias;
    const u16* Bpl = Bl;
    if (MODE >= 2) {
        if (m0 >= asg[8]) return;
        int e = 0;
        while (m0 >= asg[e + 1]) ++e;    // uniform across block
        Bph = Bh + (size_t)e * N * K;
        bp = bias + (size_t)e * N;
    }
    int kbeg = 0, kend = K;
    if (MODE == 3) { int kh = K >> 1; kbeg = zt * kh; kend = kbeg + kh; }

    // LDS pool. SPLIT: 2 bufs x {Ah,Bh,Al,Bl} x 8KB = 64KB. MODE2/3: 3 bufs x {A,B} x 8KB = 48KB
    // (MODE2 epilogue reuses first 32KB as the 128x128 bf16 C-tile).
    __shared__ __align__(16) u16 SM[SPLIT ? 32768 : 24576];
    u16* Ash = SM;
    u16* Bsh = SM + (SPLIT ? 8192 : 12288);
    u16* Asl = SM + 16384;   // SPLIT only
    u16* Bsl = SM + 24576;   // SPLIT only

    int tid = threadIdx.x;
    int w = tid >> 6, lane = tid & 63, l15 = lane & 15, quad = lane >> 4;
    int wm = (w & 1) * 64, wn = (w >> 1) * 64;
    int lr = lane >> 2;
    // source granule swizzle: LDS slot (row=lane>>2, gpos=lane&3) holds logical granule
    // gpos ^ ((row>>1)&3); since (lane>>3)&3 == (tile_row>>1)&3 this is per-lane source math only.
    int lc = ((lane & 3) ^ ((lane >> 3) & 3)) * 8;

    const u16* ga[2]; const u16* gal[2];
    const u16* gb[2]; const u16* gbl[2];
    int ldro[2];
#pragma unroll
    for (int it = 0; it < 2; it++) {
        int arow = m0 + it * 64 + w * 16 + lr;
        if (MODE == 2) {
            int entry = list[arow];
            ga[it] = Ah + (size_t)(entry >= 0 ? (entry >> 1) : 0) * K + lc;  // invalid -> row0, store-guarded
        } else if (MODE == 3) {
            ga[it] = Ah + (size_t)arow * K + lc;   // padding rows finite poison; store-guarded
        } else {
            int rc = min(arow, M - 1);
            ga[it] = Ah + (size_t)rc * K + lc;
            gal[it] = Al + (size_t)rc * K + lc;
        }
        int brow = n0 + it * 64 + w * 16 + lr;
        gb[it] = Bph + (size_t)brow * K + lc;
        if (SPLIT) gbl[it] = Bpl + (size_t)brow * K + lc;
        ldro[it] = (it * 64 + w * 16) * 32;       // wave-uniform LDS chunk base (within a buffer)
    }

    // read addresses (loop-invariant): row-major [128][32] with XOR granule de-swizzle
    int ra[4], rb[4];
#pragma unroll
    for (int i = 0; i < 4; i++) {
        int r1 = wm + i * 16 + l15;
        ra[i] = r1 * 32 + (quad ^ ((r1 >> 1) & 3)) * 8;
        int r2 = wn + i * 16 + l15;
        rb[i] = r2 * 32 + (quad ^ ((r2 >> 1) & 3)) * 8;
    }

    floatx4 acc[4][4];
#pragma unroll
    for (int mi = 0; mi < 4; mi++)
#pragma unroll
        for (int ni = 0; ni < 4; ni++) acc[mi][ni] = (floatx4){0.f, 0.f, 0.f, 0.f};

    auto stage = [&](int buf, int k0) {
        int bo = buf * 4096;
#pragma unroll
        for (int it = 0; it < 2; it++) {
            gl_lds16(ga[it] + k0, &Ash[bo + ldro[it]]);
            gl_lds16(gb[it] + k0, &Bsh[bo + ldro[it]]);
            if constexpr (SPLIT) {
                gl_lds16(gal[it] + k0, &Asl[bo + ldro[it]]);
                gl_lds16(gbl[it] + k0, &Bsl[bo + ldro[it]]);
            }
        }
    };
    auto compute = [&](int buf) {
        int bo = buf * 4096;
        bf16x8 afh[4], bfh[4], afl[4], bfl[4];
#pragma unroll
        for (int i = 0; i < 4; i++) {
            afh[i] = *(const bf16x8*)&Ash[bo + ra[i]];
            bfh[i] = *(const bf16x8*)&Bsh[bo + rb[i]];
            if constexpr (SPLIT) {
                afl[i] = *(const bf16x8*)&Asl[bo + ra[i]];
                bfl[i] = *(const bf16x8*)&Bsl[bo + rb[i]];
            }
        }
        __builtin_amdgcn_s_setprio(1);
#pragma unroll
        for (int mi = 0; mi < 4; mi++)
#pragma unroll
            for (int ni = 0; ni < 4; ni++) {
                if constexpr (SPLIT) {
                    acc[mi][ni] = __builtin_amdgcn_mfma_f32_16x16x32_bf16(afl[mi], bfh[ni], acc[mi][ni], 0, 0, 0);
                    acc[mi][ni] = __builtin_amdgcn_mfma_f32_16x16x32_bf16(afh[mi], bfl[ni], acc[mi][ni], 0, 0, 0);
                }
                acc[mi][ni] = __builtin_amdgcn_mfma_f32_16x16x32_bf16(afh[mi], bfh[ni], acc[mi][ni], 0, 0, 0);
            }
        __builtin_amdgcn_s_setprio(0);
    };

    int nsteps = (kend - kbeg) >> 5;
    if constexpr (SPLIT) {
        // 2-buffer counted-vmcnt single-barrier pipeline: loads stay in flight across the barrier.
        stage(0, kbeg);
        stage(1, kbeg + 32);
        asm volatile("s_waitcnt vmcnt(8)" ::: "memory");   // buf0's 8 landed (buf1's 8 in flight)
        __builtin_amdgcn_s_barrier();
        for (int t = 0; t < nsteps; ++t) {
            compute(t & 1);
            asm volatile("s_waitcnt lgkmcnt(0)" ::: "memory");  // my reads of buf t done
            __builtin_amdgcn_s_barrier();                        // all waves done reading buf t
            if (t + 2 < nsteps) {
                stage(t & 1, kbeg + (t + 2) * 32);               // overwrite buf t for step t+2
                asm volatile("s_waitcnt vmcnt(8)" ::: "memory"); // buf t+1 landed; newest 8 in flight
            } else if (t + 1 < nsteps) {
                asm volatile("s_waitcnt vmcnt(0)" ::: "memory"); // drain for final step
            }
        }
    } else {
        // depth-3 counted-vmcnt pipeline (r4-proven); 4 gl_lds per stage per wave.
        stage(0, kbeg);
        stage(1, kbeg + 32);
        asm volatile("s_waitcnt vmcnt(4)" ::: "memory");   // buf0 landed (buf1 = 4 in flight)
        __builtin_amdgcn_s_barrier();
        int bufc = 0;
        for (int t = 0; t < nsteps; ++t) {
            int b2 = bufc + 2; if (b2 >= 3) b2 -= 3;
            if (t + 2 < nsteps) stage(b2, kbeg + (t + 2) * 32);   // overwrites buf(t-1): freed by prev barrier
            compute(bufc);
            if (t + 2 < nsteps) {
                asm volatile("s_waitcnt vmcnt(4) lgkmcnt(0)" ::: "memory");
            } else {
                asm volatile("s_waitcnt vmcnt(0) lgkmcnt(0)" ::: "memory");
            }
            __builtin_amdgcn_s_barrier();
            bufc = (bufc == 2) ? 0 : bufc + 1;
        }
    }

    if constexpr (MODE == 2) {
        // stage gelu(bf16) tile into SM[128][128] (col XOR-swizzled), then coalesced row stores
#pragma unroll
        for (int ni = 0; ni < 4; ni++) {
            int col = wn + ni * 16 + l15;
            float bb = bp[n0 + col];
#pragma unroll
            for (int mi = 0; mi < 4; mi++) {
#pragma unroll
                for (int r = 0; r < 4; r++) {
                    int row = wm + mi * 16 + quad * 4 + r;
                    float gv = gelu_fast(acc[mi][ni][r] + bb);
                    SM[row * 128 + (col ^ ((row & 7) << 3))] = f2bf(gv);
                }
            }
        }
        __syncthreads();
        int rr = tid >> 1, half = (tid & 1) * 64;
        int grow = m0 + rr;
        if (list[grow] >= 0) {
            u16* dst = (u16*)Cv + (size_t)grow * N + n0 + half;
            int xr = (rr & 7) << 3;
#pragma unroll
            for (int gch = 0; gch < 8; gch++) {
                int cb = (half + gch * 8) ^ xr;
                *(uint4*)(dst + gch * 8) = *(const uint4*)&SM[rr * 128 + cb];
            }
        }
        return;
    }

    float* Cf = (float*)Cv;
    if (MODE == 3 && zt != 0) Cf = (float*)Cv2;
#pragma unroll
    for (int ni = 0; ni < 4; ni++) {
        int col = n0 + wn + ni * 16 + l15;
        float bb = bp[col];
        if (MODE == 3 && zt != 0) bb = 0.f;   // bias added once (z=0 half)
#pragma unroll
        for (int mi = 0; mi < 4; mi++) {
#pragma unroll
            for (int r = 0; r < 4; r++) {
                int row = m0 + wm + mi * 16 + quad * 4 + r;
                float v2 = acc[mi][ni][r] + bb;
                if (MODE == 0) {
                    if (row < M) {
                        u16 hb = f2bf(v2);
                        ((u16*)Cv)[(size_t)row * N + col] = hb;
                        ((u16*)Cv2)[(size_t)row * N + col] = f2bf(v2 - bf2f(hb));
                    }
                } else if (MODE == 1) {
                    if (row < M) Cf[(size_t)row * N + col] = v2 + resid[(size_t)row * N + col];
                } else {
                    if (list[row] >= 0) Cf[(size_t)row * N + col] = v2;
                }
            }
        }
    }
}

// ---------------- MFMA attention: bf16 hi/lo qkv planes; block = (b, h, 64-q-tile), 4 waves ----------------
__global__ __launch_bounds__(256) void attn_mfma_kernel(const u16* __restrict__ qph,
        const u16* __restrict__ qpl, u16* __restrict__ ohi, u16* __restrict__ olo) {
    // bijective XCD swizzle over 768 blocks: XCD j gets 24 consecutive (b,h) with all 4 q-tiles
    int d = blockIdx.x + 4 * blockIdx.y;
    int j = d & 7, sdx = d >> 3;
    int v = j * 96 + sdx;
    int qbase = (v & 3) * 64;
    int by = v >> 2;
    int b = by / NH, h = by % NH;
    int tid = threadIdx.x;
    int w = tid >> 6, lane = tid & 63, l15 = lane & 15, quad = lane >> 4;

    __shared__ u16 Qh[64 * 64], Ql[64 * 64];
    __shared__ u16 Sh[64 * 64], Sl[64 * 64];   // K tile, then V^T tile
    __shared__ u16 Ph[64 * 72], Pl[64 * 72];

    int grow8 = lane >> 3;                     // row within 8-row gl_lds group
    int gsrc = ((lane & 7) ^ grow8) * 8;       // swizzled source granule (u16 offset)
    int srow = tid >> 2;                       // V^T: key index
    int scol = (tid & 3) * 16;                 // V^T: d base

    // --- stage Q (gl_lds, swizzled) ---
#pragma unroll
    for (int it = 0; it < 2; it++) {
        int r = qbase + w * 16 + it * 8 + grow8;
        int rc = min(r, SEQ - 1);
        size_t so = (size_t)(b * SEQ + rc) * 2304 + h * 64 + gsrc;
        gl_lds16(qph + so, &Qh[(w * 16 + it * 8) * 64]);
        gl_lds16(qpl + so, &Ql[(w * 16 + it * 8) * 64]);
    }
    __syncthreads();
    bf16x8 aqh[2], aql[2];
#pragma unroll
    for (int s2 = 0; s2 < 2; s2++) {
        int row = w * 16 + l15;
        int ad = row * 64 + (((s2 * 4 + quad) ^ (row & 7))) * 8;
        aqh[s2] = *(const bf16x8*)&Qh[ad];
        aql[s2] = *(const bf16x8*)&Ql[ad];
    }

    floatx4 sc[16];
#pragma unroll
    for (int f = 0; f < 16; f++) sc[f] = (floatx4){0.f, 0.f, 0.f, 0.f};

    for (int t = 0; t < 4; t++) {
#pragma unroll
        for (int it = 0; it < 2; it++) {
            int r = t * 64 + w * 16 + it * 8 + grow8;
            int rc = min(r, SEQ - 1);
            size_t so = (size_t)(b * SEQ + rc) * 2304 + 768 + h * 64 + gsrc;
            gl_lds16(qph + so, &Sh[(w * 16 + it * 8) * 64]);
            gl_lds16(qpl + so, &Sl[(w * 16 + it * 8) * 64]);
        }
        __syncthreads();
#pragma unroll
        for (int s = 0; s < 4; s++) {
            int row = s * 16 + l15;
#pragma unroll
            for (int s2 = 0; s2 < 2; s2++) {
                int ad = row * 64 + (((s2 * 4 + quad) ^ (row & 7))) * 8;
                bf16x8 bkh = *(const bf16x8*)&Sh[ad];
                bf16x8 bkl = *(const bf16x8*)&Sl[ad];
                sc[t * 4 + s] = __builtin_amdgcn_mfma_f32_16x16x32_bf16(aql[s2], bkh, sc[t * 4 + s], 0, 0, 0);
                sc[t * 4 + s] = __builtin_amdgcn_mfma_f32_16x16x32_bf16(aqh[s2], bkl, sc[t * 4 + s], 0, 0, 0);
                sc[t * 4 + s] = __builtin_amdgcn_mfma_f32_16x16x32_bf16(aqh[s2], bkh, sc[t * 4 + s], 0, 0, 0);
            }
        }
        __syncthreads();
    }

    float m[4] = {-1e30f, -1e30f, -1e30f, -1e30f};
#pragma unroll
    for (int f = 0; f < 16; f++) {
        int key = (f >> 2) * 64 + (f & 3) * 16 + l15;
        bool valid = key < SEQ;
#pragma unroll
        for (int r = 0; r < 4; r++) {
            float s = valid ? sc[f][r] * 0.125f : -1e30f;
            sc[f][r] = s;
            m[r] = fmaxf(m[r], s);
        }
    }
#pragma unroll
    for (int r = 0; r < 4; r++) {
#pragma unroll
        for (int off = 1; off < 16; off <<= 1) m[r] = fmaxf(m[r], __shfl_xor(m[r], off));
    }
    float sum[4] = {0.f, 0.f, 0.f, 0.f};
#pragma unroll
    for (int f = 0; f < 16; f++) {
#pragma unroll
        for (int r = 0; r < 4; r++) {
            float p = expf(sc[f][r] - m[r]);
            sc[f][r] = p;
            sum[r] += p;
        }
    }
    float inv[4];
#pragma unroll
    for (int r = 0; r < 4; r++) {
#pragma unroll
        for (int off = 1; off < 16; off <<= 1) sum[r] += __shfl_xor(sum[r], off);
        inv[r] = 1.f / sum[r];
    }

    floatx4 oacc[4];
#pragma unroll
    for (int sd = 0; sd < 4; sd++) oacc[sd] = (floatx4){0.f, 0.f, 0.f, 0.f};

    for (int t = 0; t < 4; t++) {
#pragma unroll
        for (int s = 0; s < 4; s++) {
#pragma unroll
            for (int r = 0; r < 4; r++) {
                float p = sc[t * 4 + s][r];
                u16 hb = f2bf(p);
                int row = w * 16 + quad * 4 + r;
                Ph[row * 72 + s * 16 + l15] = hb;
                Pl[row * 72 + s * 16 + l15] = f2bf(p - bf2f(hb));
            }
        }
        {
            // V^T staging from bf16 planes (u16-only), granule-swizzled for conflict-free reads
            int key = t * 64 + srow;
            int kc = min(key, SEQ - 1);   // garbage rows hit P==0 (masked scores), finite => safe
            size_t so = (size_t)(b * SEQ + kc) * 2304 + 1536 + h * 64 + scol;
            u16 hv[16], lv[16];
            *(uint4*)&hv[0] = *(const uint4*)(qph + so);
            *(uint4*)&hv[8] = *(const uint4*)(qph + so + 8);
            *(uint4*)&lv[0] = *(const uint4*)(qpl + so);
            *(uint4*)&lv[8] = *(const uint4*)(qpl + so + 8);
            int kg = srow >> 3, kw = srow & 7;
#pragma unroll
            for (int i = 0; i < 16; i++) {
                int dcol = scol + i;
                int idx2 = dcol * 64 + ((kg ^ (dcol & 7)) * 8) + kw;
                Sh[idx2] = hv[i];
                Sl[idx2] = lv[i];
            }
        }
        __syncthreads();
#pragma unroll
        for (int s2 = 0; s2 < 2; s2++) {
            bf16x8 aph = *(const bf16x8*)&Ph[(w * 16 + l15) * 72 + s2 * 32 + quad * 8];
            bf16x8 apl = *(const bf16x8*)&Pl[(w * 16 + l15) * 72 + s2 * 32 + quad * 8];
#pragma unroll
            for (int sd = 0; sd < 4; sd++) {
                int row = sd * 16 + l15;
                int ad = row * 64 + (((s2 * 4 + quad) ^ (row & 7))) * 8;
                bf16x8 bvh = *(const bf16x8*)&Sh[ad];
                bf16x8 bvl = *(const bf16x8*)&Sl[ad];
                oacc[sd] = __builtin_amdgcn_mfma_f32_16x16x32_bf16(apl, bvh, oacc[sd], 0, 0, 0);
                oacc[sd] = __builtin_amdgcn_mfma_f32_16x16x32_bf16(aph, bvl, oacc[sd], 0, 0, 0);
                oacc[sd] = __builtin_amdgcn_mfma_f32_16x16x32_bf16(aph, bvh, oacc[sd], 0, 0, 0);
            }
        }
        __syncthreads();
    }

#pragma unroll
    for (int sd = 0; sd < 4; sd++) {
#pragma unroll
        for (int r = 0; r < 4; r++) {
            int q = qbase + w * 16 + quad * 4 + r;
            if (q < SEQ) {
                float val = oacc[sd][r] * inv[r];
                u16 hb = f2bf(val);
                size_t o = ((size_t)(b * SEQ + q)) * 768 + h * 64 + sd * 16 + l15;
                ohi[o] = hb;
                olo[o] = f2bf(val - bf2f(hb));
            }
        }
    }
}

// ---------------- w_gate transpose: wg[768][8] -> wgT[8][768] (tiny, 1 block) ----------------
__global__ void wgt_kernel(const float* __restrict__ wg, float* __restrict__ wgT) {
    for (int i = threadIdx.x; i < 768 * 8; i += 256) {
        int d = i >> 3, e = i & 7;
        wgT[e * 768 + d] = wg[i];
    }
}

// ---------------- LN2 + gate (top-2 of 8): one WAVE per token, no LDS, no barriers, no atomics ----------------
__global__ __launch_bounds__(256) void ln2_gate_kernel(const float* __restrict__ x1,
        const float* __restrict__ g, const float* __restrict__ b, const float* __restrict__ wgT,
        u16* __restrict__ flat, int2* __restrict__ idx, float2* __restrict__ gate) {
    int w = threadIdx.x >> 6, lane = threadIdx.x & 63;
    int t = blockIdx.x * 4 + w;
    if (t >= T_TOK) return;
    const float* xp = x1 + (size_t)t * 768;
    float v[3][4];
    float s = 0.f, q = 0.f;
#pragma unroll
    for (int i = 0; i < 3; i++) {
        float4 f4 = *(const float4*)(xp + i * 256 + lane * 4);
        v[i][0] = f4.x; v[i][1] = f4.y; v[i][2] = f4.z; v[i][3] = f4.w;
#pragma unroll
        for (int j2 = 0; j2 < 4; j2++) { s += v[i][j2]; q += v[i][j2] * v[i][j2]; }
    }
    s = wred_sum(s); q = wred_sum(q);
    float mean = s * (1.f / 768.f);
    float var = q * (1.f / 768.f) - mean * mean;
    float rs = rsqrtf(var + 1e-5f);
    float fs[3][4];
#pragma unroll
    for (int i = 0; i < 3; i++) {
        int d0 = i * 256 + lane * 4;
        float4 g4 = *(const float4*)(g + d0);
        float4 b4 = *(const float4*)(b + d0);
        float gg[4] = {g4.x, g4.y, g4.z, g4.w};
        float bb[4] = {b4.x, b4.y, b4.z, b4.w};
        u16 hv[4];
#pragma unroll
        for (int j2 = 0; j2 < 4; j2++) {
            float f = (v[i][j2] - mean) * rs * gg[j2] + bb[j2];
            fs[i][j2] = f;
            hv[j2] = f2bf(f);
        }
        *(uint2*)&flat[(size_t)t * 768 + d0] = *(const uint2*)hv;
    }
    float lg[8];
#pragma unroll
    for (int e = 0; e < 8; e++) {
        float p = 0.f;
#pragma unroll
        for (int i = 0; i < 3; i++) {
            float4 wv = *(const float4*)(wgT + e * 768 + i * 256 + lane * 4);
            p = fmaf(fs[i][0], wv.x, p);
            p = fmaf(fs[i][1], wv.y, p);
            p = fmaf(fs[i][2], wv.z, p);
            p = fmaf(fs[i][3], wv.w, p);
        }
        lg[e] = wred_sum(p);
    }
    if (lane == 0) {
        float b0 = -1e30f, b1 = -1e30f;
        int i0 = 0, i1 = 0;
#pragma unroll
        for (int e = 0; e < 8; e++) {     // strict > keeps first occurrence (jax tie-break)
            float le = lg[e];
            if (le > b0) { b1 = b0; i1 = i0; b0 = le; i0 = e; }
            else if (le > b1) { b1 = le; i1 = e; }
        }
        float ex = expf(b1 - b0);
        float den = 1.f + ex;
        idx[t] = make_int2(i0, i1);
        gate[t] = make_float2(1.f / den, ex / den);
    }
}

// ---------------- routing: 1-block atomic-free histogram + offsets + deterministic scatter ----------------
__global__ __launch_bounds__(256) void route_kernel(const int2* __restrict__ idx,
        int* __restrict__ asg, int* __restrict__ list, int* __restrict__ pos) {
    int tid = threadIdx.x, w = tid >> 6, lane = tid & 63;
    __shared__ int wcnt[4][8];
    __shared__ int run[8];

    // phase 1: histogram via register counts + wave reduce (no atomics)
    int myc[8] = {0, 0, 0, 0, 0, 0, 0, 0};
    for (int t = tid; t < T_TOK; t += 256) {
        int2 id = idx[t];
#pragma unroll
        for (int e = 0; e < 8; e++) myc[e] += (id.x == e) + (id.y == e);
    }
#pragma unroll
    for (int e = 0; e < 8; e++) {
        int c = wred_sum_i(myc[e]);
        if (lane == 0) wcnt[w][e] = c;
    }
    __syncthreads();
    if (tid == 0) {
        int acc = 0;
        for (int e = 0; e < 8; e++) {
            run[e] = acc;
            asg[e] = acc;
            int c = wcnt[0][e] + wcnt[1][e] + wcnt[2][e] + wcnt[3][e];
            acc += (c + 127) & ~127;
        }
        asg[8] = acc;
    }
    __syncthreads();

    // phase 2: deterministic scatter via ballot prefix ranks (entry order: token, then x before y)
    unsigned long long lt = (1ull << lane) - 1ull;   // lanes below me (lane<64, no UB for 63)
    for (int c0 = 0; c0 < T_TOK; c0 += 256) {
        int t = c0 + tid;
        bool valid = t < T_TOK;
        int ex = valid ? idx[t].x : -1;
        int ey = valid ? idx[t].y : -1;
        int rkx = 0, rky = 0;
        int wtot[8];
#pragma unroll
        for (int e = 0; e < 8; e++) {
            unsigned long long mx = __ballot(ex == e);
            unsigned long long my = __ballot(ey == e);
            int r = __popcll(mx & lt) + __popcll(my & lt);
            if (ex == e) rkx = r;
            if (ey == e) rky = r;       // own x-entry targets ex != ey, contributes 0
            wtot[e] = __popcll(mx) + __popcll(my);
        }
        if (lane == 0) {
#pragma unroll
            for (int e = 0; e < 8; e++) wcnt[w][e] = wtot[e];
        }
        __syncthreads();
        if (valid) {
            int wpx = 0, wpy = 0;
            for (int w2 = 0; w2 < w; w2++) { wpx += wcnt[w2][ex]; wpy += wcnt[w2][ey]; }
            int p0 = run[ex] + wpx + rkx;
            int p1 = run[ey] + wpy + rky;
            list[p0] = t * 2;
            pos[t * 2] = p0;
            list[p1] = t * 2 + 1;
            pos[t * 2 + 1] = p1;
        }
        __syncthreads();
        if (tid < 8) run[tid] += wcnt[0][tid] + wcnt[1][tid] + wcnt[2][tid] + wcnt[3][tid];
        __syncthreads();
    }
}

// ---------------- final: out = x1 + g0*(y0[p0]+y1[p0]) + g1*(y0[p1]+y1[p1])  (f32 out) ----------------
__global__ __launch_bounds__(256) void final_kernel(const float* __restrict__ x1,
        const float* __restrict__ yp0, const float* __restrict__ yp1, const int* __restrict__ pos,
        const float2* __restrict__ gate, float* __restrict__ out) {
    int t = blockIdx.x, tid = threadIdx.x;
    float2 g = gate[t];
    int p0 = pos[t * 2], p1 = pos[t * 2 + 1];
#pragma unroll
    for (int i = 0; i < 3; i++) {
        int d = tid + i * 256;
        float y0 = yp0[(size_t)p0 * 768 + d] + yp1[(size_t)p0 * 768 + d];
        float y1 = yp0[(size_t)p1 * 768 + d] + yp1[(size_t)p1 * 768 + d];
        out[(size_t)t * 768 + d] = x1[(size_t)t * 768 + d] + g.x * y0 + g.y * y1;
    }
}

extern "C" void kernel_launch(void* const* d_in, const int* in_sizes, int n_in,
                              void* d_out, int out_size, void* d_ws, size_t ws_size,
                              hipStream_t stream) {
    const float* x      = (const float*)d_in[0];
    const float* ln1_g  = (const float*)d_in[1];
    const float* ln1_b  = (const float*)d_in[2];
    const float* qkv_w  = (const float*)d_in[3];
    const float* qkv_b  = (const float*)d_in[4];
    const float* proj_w = (const float*)d_in[5];
    const float* proj_b = (const float*)d_in[6];
    const float* ln2_g  = (const float*)d_in[7];
    const float* ln2_b  = (const float*)d_in[8];
    const float* w_gate = (const float*)d_in[9];
    const float* w1     = (const float*)d_in[10];
    const float* b1     = (const float*)d_in[11];
    const float* w2     = (const float*)d_in[12];
    const float* b2     = (const float*)d_in[13];

    char* ws = (char*)d_ws;
    size_t off = 0;
    auto alloc = [&](size_t bytes) { size_t cur = off; off = (off + bytes + 255) & ~(size_t)255; return cur; };
    // region0: h_hi|h_lo|qkv_hi|qkv_lo|o_hi|o_lo (dead before MoE2) — reused as ypair0 (22.8MB <= 48.4MB)
    u16*    h_hi   = (u16*)   (ws + alloc((size_t)T_TOK * 768 * 2));
    u16*    h_lo   = (u16*)   (ws + alloc((size_t)T_TOK * 768 * 2));
    u16*    qkv_hi = (u16*)   (ws + alloc((size_t)T_TOK * 2304 * 2));
    u16*    qkv_lo = (u16*)   (ws + alloc((size_t)T_TOK * 2304 * 2));
    u16*    o_hi   = (u16*)   (ws + alloc((size_t)T_TOK * 768 * 2));
    u16*    o_lo   = (u16*)   (ws + alloc((size_t)T_TOK * 768 * 2));
    float*  ypair0 = (float*) ws;   // 7424*768*4 = 22.8MB <= region0
    float*  x1     = (float*) (ws + alloc((size_t)T_TOK * 768 * 4));
    u16*    flat   = (u16*)   (ws + alloc((size_t)T_TOK * 768 * 2));
    int2*   idx    = (int2*)  (ws + alloc((size_t)T_TOK * 8));
    float2* gate   = (float2*)(ws + alloc((size_t)T_TOK * 8));
    float*  wgT    = (float*) (ws + alloc((size_t)8 * 768 * 4));
    int*    asg    = (int*)   (ws + alloc(64));     // aligned_start[9]
    int*    list   = (int*)   (ws + alloc((size_t)LISTN * 4));
    int*    pos    = (int*)   (ws + alloc((size_t)T_TOK * 2 * 4));
    u16*    hid    = (u16*)   (ws + alloc((size_t)LISTN * 3072 * 2));
    u16*    qkvt_h = (u16*)   (ws + alloc((size_t)2304 * 768 * 2));
    u16*    qkvt_l = (u16*)   (ws + alloc((size_t)2304 * 768 * 2));
    u16*    projt_h = (u16*)  (ws + alloc((size_t)768 * 768 * 2));
    u16*    projt_l = (u16*)  (ws + alloc((size_t)768 * 768 * 2));
    u16*    w1t    = (u16*)   (ws + alloc((size_t)8 * 3072 * 768 * 2));
    u16*    w2t    = (u16*)   (ws + alloc((size_t)8 * 768 * 3072 * 2));
    float*  ypair1 = (float*) w1t;  // w1t (37.7MB) dead after moe1; ypair1 needs 22.8MB

    hipMemsetAsync(list, 0xFF, (size_t)LISTN * 4, stream);

    // weight prep (bf16, [n][k] layout; qkv/proj split hi/lo) + gate transpose
    transp_kernel<1><<<dim3(12, 36, 1), 256, 0, stream>>>(qkv_w, qkvt_h, qkvt_l, 768, 2304);
    transp_kernel<1><<<dim3(12, 12, 1), 256, 0, stream>>>(proj_w, projt_h, projt_l, 768, 768);
    transp_kernel<0><<<dim3(12, 48, 8), 256, 0, stream>>>(w1, w1t, nullptr, 768, 3072);
    transp_kernel<0><<<dim3(48, 12, 8), 256, 0, stream>>>(w2, w2t, nullptr, 3072, 768);
    wgt_kernel<<<1, 256, 0, stream>>>(w_gate, wgT);

    ln1_kernel<<<T_TOK, 256, 0, stream>>>(x, ln1_g, ln1_b, h_hi, h_lo);
    gemm128<0><<<dim3(25, 18), 256, 0, stream>>>(h_hi, h_lo, qkvt_h, qkvt_l, qkv_b, qkv_hi,
                                                 qkv_lo, nullptr, nullptr, nullptr, T_TOK, 2304, 768);
    attn_mfma_kernel<<<dim3(4, 192), 256, 0, stream>>>(qkv_hi, qkv_lo, o_hi, o_lo);
    gemm128<1><<<dim3(25, 6), 256, 0, stream>>>(o_hi, o_lo, projt_h, projt_l, proj_b, x1,
                                                nullptr, x, nullptr, nullptr, T_TOK, 768, 768);
    ln2_gate_kernel<<<T_TOK / 4, 256, 0, stream>>>(x1, ln2_g, ln2_b, wgT, flat, idx, gate);
    route_kernel<<<1, 256, 0, stream>>>(idx, asg, list, pos);
    gemm128<2><<<dim3(MOE_MT, 24), 256, 0, stream>>>(flat, nullptr, w1t, nullptr, b1, hid,
                                                     nullptr, nullptr, list, asg, LISTN, 3072, 768);
    gemm128<3><<<dim3(MOE_MT, 6, 2), 256, 0, stream>>>(hid, nullptr, w2t, nullptr, b2, ypair0,
                                                       ypair1, nullptr, list, asg, LISTN, 768, 3072);
    final_kernel<<<T_TOK, 256, 0, stream>>>(x1, ypair0, ypair1, pos, gate, (float*)d_out);
}

// Round 12
// 489.502 us; speedup vs baseline: 1.3358x; 1.0230x over previous
//
#include <hip/hip_runtime.h>
#include <math.h>
#include <stdint.h>

typedef unsigned short u16;
typedef unsigned int u32;
typedef float floatx4 __attribute__((ext_vector_type(4)));
typedef __bf16 bf16x8 __attribute__((ext_vector_type(8)));

#define T_TOK 3152      // B*L = 16*197
#define SEQ 197
#define NH 12
#define LISTN 7424      // 58 tiles * 128 (worst-case 128-aligned expert segments)
#define MOE_MT 58

__device__ __forceinline__ float bf2f(u16 u) { return __uint_as_float(((u32)u) << 16); }
__device__ __forceinline__ u16 f2bf(float f) {
    u32 u = __float_as_uint(f);
    u += 0x7FFFu + ((u >> 16) & 1u);   // RNE
    return (u16)(u >> 16);
}
__device__ __forceinline__ float wred_sum(float v) {
#pragma unroll
    for (int off = 32; off; off >>= 1) v += __shfl_xor(v, off);
    return v;
}
__device__ __forceinline__ int wred_sum_i(int v) {
#pragma unroll
    for (int off = 32; off; off >>= 1) v += __shfl_xor(v, off);
    return v;
}

// fast exact-enough gelu: A&S 7.1.26 erf, |err| <= 1.5e-7 (abs) -> bf16-identical vs erff
__device__ __forceinline__ float gelu_fast(float v) {
    float x = fabsf(v) * 0.70710678118654752f;
    float t = __builtin_amdgcn_rcpf(fmaf(0.3275911f, x, 1.0f));
    float p = t * fmaf(t, fmaf(t, fmaf(t, fmaf(t, 1.061405429f, -1.453152027f),
                                       1.421413741f), -0.284496736f), 0.254829592f);
    float er = fmaf(-p, __expf(-x * x), 1.0f);   // erf(|x|)
    er = copysignf(er, v);
    return 0.5f * v * (1.0f + er);
}

// async global->LDS, 16B per lane; LDS dest must be wave-uniform base (+lane*16 implicit)
#define GLB_AS(p) ((const __attribute__((address_space(1))) void*)(uintptr_t)(p))
#define LDS_AS(p) ((__attribute__((address_space(3))) void*)(uintptr_t)(p))
__device__ __forceinline__ void gl_lds16(const u16* g, u16* l) {
    __builtin_amdgcn_global_load_lds(GLB_AS(g), LDS_AS(l), 16, 0, 0);
}

// ---------------- fused weight prep ----------------
// transp tile: in f32 [z][R][C] -> out bf16 [z][C][R] (opt split hi/lo), 64x64 per block
__device__ __forceinline__ void transp_tile(const float* __restrict__ in,
        u16* __restrict__ oh, u16* __restrict__ ol, int R, int C,
        int rt, int ct, int z, bool split, float (*Lt)[68]) {
    int r0 = rt * 64, c0 = ct * 64;
    size_t zo = (size_t)z * R * C;
    int tid = threadIdx.x;
    int rr = tid >> 2, cs = (tid & 3) * 16;
    const float* src = in + zo + (size_t)(r0 + rr) * C + c0 + cs;
#pragma unroll
    for (int i = 0; i < 4; i++) *(float4*)&Lt[rr][cs + i * 4] = *(const float4*)(src + i * 4);
    __syncthreads();
    int cw = tid >> 2, rs = (tid & 3) * 16;
    u16 hv[16], lv[16];
#pragma unroll
    for (int j2 = 0; j2 < 16; j2++) {
        float v = Lt[rs + j2][cw];
        u16 hb = f2bf(v);
        hv[j2] = hb;
        if (split) lv[j2] = f2bf(v - bf2f(hb));
    }
    u16* dst = oh + zo + (size_t)(c0 + cw) * R + r0 + rs;
    *(uint4*)dst = *(const uint4*)&hv[0];
    *(uint4*)(dst + 8) = *(const uint4*)&hv[8];
    if (split) {
        u16* dstl = ol + zo + (size_t)(c0 + cw) * R + r0 + rs;
        *(uint4*)dstl = *(const uint4*)&lv[0];
        *(uint4*)(dstl + 8) = *(const uint4*)&lv[8];
    }
}

#define PREP_QKVT 432   // 12 x 36
#define PREP_PROJT 144  // 12 x 12
#define PREP_W1T 4608   // 12 x 48 x 8
#define PREP_W2T 4608   // 48 x 12 x 8
#define PREP_TOTAL (PREP_QKVT + PREP_PROJT + PREP_W1T + PREP_W2T + 1)

__global__ __launch_bounds__(256) void prep_kernel(
        const float* __restrict__ qkv_w, u16* __restrict__ qkvt_h, u16* __restrict__ qkvt_l,
        const float* __restrict__ proj_w, u16* __restrict__ projt_h, u16* __restrict__ projt_l,
        const float* __restrict__ w1, u16* __restrict__ w1t,
        const float* __restrict__ w2, u16* __restrict__ w2t,
        const float* __restrict__ wg, float* __restrict__ wgT) {
    __shared__ float Lt[64][68];
    int bid = blockIdx.x;
    if (bid < PREP_QKVT) {
        transp_tile(qkv_w, qkvt_h, qkvt_l, 768, 2304, bid % 12, bid / 12, 0, true, Lt);
    } else if (bid < PREP_QKVT + PREP_PROJT) {
        int lb = bid - PREP_QKVT;
        transp_tile(proj_w, projt_h, projt_l, 768, 768, lb % 12, lb / 12, 0, true, Lt);
    } else if (bid < PREP_QKVT + PREP_PROJT + PREP_W1T) {
        int lb = bid - (PREP_QKVT + PREP_PROJT);
        int z = lb / (12 * 48), rem = lb % (12 * 48);
        transp_tile(w1, w1t, nullptr, 768, 3072, rem % 12, rem / 12, z, false, Lt);
    } else if (bid < PREP_QKVT + PREP_PROJT + PREP_W1T + PREP_W2T) {
        int lb = bid - (PREP_QKVT + PREP_PROJT + PREP_W1T);
        int z = lb / (48 * 12), rem = lb % (48 * 12);
        transp_tile(w2, w2t, nullptr, 3072, 768, rem % 48, rem / 48, z, false, Lt);
    } else {
        for (int i = threadIdx.x; i < 768 * 8; i += 256) {
            int d2 = i >> 3, e = i & 7;
            wgT[e * 768 + d2] = wg[i];
        }
    }
}

// ---------------- LN1: h = LN(x)*g+b, split to bf16 hi/lo planes ----------------
__global__ __launch_bounds__(256) void ln1_kernel(const float* __restrict__ x,
        const float* __restrict__ g, const float* __restrict__ b,
        u16* __restrict__ h_hi, u16* __restrict__ h_lo) {
    int t = blockIdx.x, tid = threadIdx.x;
    int w = tid >> 6, lane = tid & 63;
    float v[3];
#pragma unroll
    for (int i = 0; i < 3; i++) v[i] = x[(size_t)t * 768 + tid + i * 256];
    float s = v[0] + v[1] + v[2];
    float q = v[0] * v[0] + v[1] * v[1] + v[2] * v[2];
    s = wred_sum(s); q = wred_sum(q);
    __shared__ float red[8];
    if (lane == 0) { red[w] = s; red[4 + w] = q; }
    __syncthreads();
    float st = red[0] + red[1] + red[2] + red[3];
    float qt = red[4] + red[5] + red[6] + red[7];
    float mean = st * (1.f / 768.f);
    float var = qt * (1.f / 768.f) - mean * mean;
    float rs = rsqrtf(var + 1e-5f);
#pragma unroll
    for (int i = 0; i < 3; i++) {
        int d = tid + i * 256;
        float hv = (v[i] - mean) * rs * g[d] + b[d];
        u16 hi = f2bf(hv);
        h_hi[(size_t)t * 768 + d] = hi;
        h_lo[(size_t)t * 768 + d] = f2bf(hv - bf2f(hi));
    }
}

// ---------------- unified 128x128 MFMA GEMM ----------------
// global_load_lds staging, XCD-partitioned bijective grid swizzle, B pre-transposed bf16 [n][k].
// SPLIT modes (0/1): 2-buffer pipeline, RACE-FIXED ordering: compute -> lgkm0 -> vmcnt(0) ->
//   barrier -> stage(t+2). Every vmcnt wait precedes the barrier that guards its consumers.
// MODE 2/3: TRIPLE-buffer counted-vmcnt pipeline (r4/r10-proven 48KB config; waits before barrier).
// MODE 0: qkv split -> bf16 hi/lo planes (Cv/Cv2). MODE 1: proj split + resid -> f32.
// MODE 2: moe1 gathered A, gelu -> bf16 (LDS-coalesced stores). MODE 3: moe2 dense A -> f32,
//         split-K; z=0 -> Cv, z=1 -> Cv2 (separate buffers).
template <int MODE>
__global__ __launch_bounds__(256) void gemm128(const u16* __restrict__ Ah,
        const u16* __restrict__ Al, const u16* __restrict__ Bh, const u16* __restrict__ Bl,
        const float* __restrict__ bias, void* __restrict__ Cv, void* __restrict__ Cv2,
        const float* __restrict__ resid,
        const int* __restrict__ list, const int* __restrict__ asg, int M, int N, int K) {
    constexpr bool SPLIT = (MODE <= 1);
    constexpr int GX = (MODE <= 1) ? 25 : MOE_MT;                    // m-tiles
    constexpr int GY = (MODE == 0) ? 18 : (MODE == 2) ? 24 : 6;      // n-tiles
    constexpr int GZ = (MODE == 3) ? 2 : 1;                          // split-K
    constexpr int G  = GX * GY * GZ;
    constexpr int NT = GY * GZ;
    constexpr int Q8 = G >> 3, R8 = G & 7;

    // dispatch index -> XCD-contiguous tile id (bijective, m204 form); HW round-robins d%8 over XCDs
    int d = blockIdx.x + GX * (blockIdx.y + GY * blockIdx.z);
    int j = d & 7, s = d >> 3;
    int v = (j < R8) ? (j * (Q8 + 1) + s) : (R8 * (Q8 + 1) + (j - R8) * Q8 + s);
    int mt = v / NT, nzr = v - mt * NT;
    int yt = nzr % GY, zt = nzr / GY;
    int m0 = mt * 128, n0 = yt * 128;

    const u16* Bph = Bh;
    const float* bp = bias;
    const u16* Bpl = Bl;
    if (MODE >= 2) {
        if (m0 >= asg[8]) return;
        int e = 0;
        while (m0 >= asg[e + 1]) ++e;    // uniform across block
        Bph = Bh + (size_t)e * N * K;
        bp = bias + (size_t)e * N;
    }
    int kbeg = 0, kend = K;
    if (MODE == 3) { int kh = K >> 1; kbeg = zt * kh; kend = kbeg + kh; }

    // LDS pool. SPLIT: 2 bufs x {Ah,Bh,Al,Bl} x 8KB = 64KB. MODE2/3: 3 bufs x {A,B} x 8KB = 48KB
    // (MODE2 epilogue reuses first 32KB as the 128x128 bf16 C-tile).
    __shared__ __align__(16) u16 SM[SPLIT ? 32768 : 24576];
    u16* Ash = SM;
    u16* Bsh = SM + (SPLIT ? 8192 : 12288);
    u16* Asl = SM + 16384;   // SPLIT only
    u16* Bsl = SM + 24576;   // SPLIT only

    int tid = threadIdx.x;
    int w = tid >> 6, lane = tid & 63, l15 = lane & 15, quad = lane >> 4;
    int wm = (w & 1) * 64, wn = (w >> 1) * 64;
    int lr = lane >> 2;
    // source granule swizzle: LDS slot (row=lane>>2, gpos=lane&3) holds logical granule
    // gpos ^ ((row>>1)&3); since (lane>>3)&3 == (tile_row>>1)&3 this is per-lane source math only.
    int lc = ((lane & 3) ^ ((lane >> 3) & 3)) * 8;

    const u16* ga[2]; const u16* gal[2];
    const u16* gb[2]; const u16* gbl[2];
    int ldro[2];
#pragma unroll
    for (int it = 0; it < 2; it++) {
        int arow = m0 + it * 64 + w * 16 + lr;
        if (MODE == 2) {
            int entry = list[arow];
            ga[it] = Ah + (size_t)(entry >= 0 ? (entry >> 1) : 0) * K + lc;  // invalid -> row0, store-guarded
        } else if (MODE == 3) {
            ga[it] = Ah + (size_t)arow * K + lc;   // padding rows finite poison; store-guarded
        } else {
            int rc = min(arow, M - 1);
            ga[it] = Ah + (size_t)rc * K + lc;
            gal[it] = Al + (size_t)rc * K + lc;
        }
        int brow = n0 + it * 64 + w * 16 + lr;
        gb[it] = Bph + (size_t)brow * K + lc;
        if (SPLIT) gbl[it] = Bpl + (size_t)brow * K + lc;
        ldro[it] = (it * 64 + w * 16) * 32;       // wave-uniform LDS chunk base (within a buffer)
    }

    // read addresses (loop-invariant): row-major [128][32] with XOR granule de-swizzle
    int ra[4], rb[4];
#pragma unroll
    for (int i = 0; i < 4; i++) {
        int r1 = wm + i * 16 + l15;
        ra[i] = r1 * 32 + (quad ^ ((r1 >> 1) & 3)) * 8;
        int r2 = wn + i * 16 + l15;
        rb[i] = r2 * 32 + (quad ^ ((r2 >> 1) & 3)) * 8;
    }

    floatx4 acc[4][4];
#pragma unroll
    for (int mi = 0; mi < 4; mi++)
#pragma unroll
        for (int ni = 0; ni < 4; ni++) acc[mi][ni] = (floatx4){0.f, 0.f, 0.f, 0.f};

    auto stage = [&](int buf, int k0) {
        int bo = buf * 4096;
#pragma unroll
        for (int it = 0; it < 2; it++) {
            gl_lds16(ga[it] + k0, &Ash[bo + ldro[it]]);
            gl_lds16(gb[it] + k0, &Bsh[bo + ldro[it]]);
            if constexpr (SPLIT) {
                gl_lds16(gal[it] + k0, &Asl[bo + ldro[it]]);
                gl_lds16(gbl[it] + k0, &Bsl[bo + ldro[it]]);
            }
        }
    };
    auto compute = [&](int buf) {
        int bo = buf * 4096;
        bf16x8 afh[4], bfh[4], afl[4], bfl[4];
#pragma unroll
        for (int i = 0; i < 4; i++) {
            afh[i] = *(const bf16x8*)&Ash[bo + ra[i]];
            bfh[i] = *(const bf16x8*)&Bsh[bo + rb[i]];
            if constexpr (SPLIT) {
                afl[i] = *(const bf16x8*)&Asl[bo + ra[i]];
                bfl[i] = *(const bf16x8*)&Bsl[bo + rb[i]];
            }
        }
        __builtin_amdgcn_s_setprio(1);
#pragma unroll
        for (int mi = 0; mi < 4; mi++)
#pragma unroll
            for (int ni = 0; ni < 4; ni++) {
                if constexpr (SPLIT) {
                    acc[mi][ni] = __builtin_amdgcn_mfma_f32_16x16x32_bf16(afl[mi], bfh[ni], acc[mi][ni], 0, 0, 0);
                    acc[mi][ni] = __builtin_amdgcn_mfma_f32_16x16x32_bf16(afh[mi], bfl[ni], acc[mi][ni], 0, 0, 0);
                }
                acc[mi][ni] = __builtin_amdgcn_mfma_f32_16x16x32_bf16(afh[mi], bfh[ni], acc[mi][ni], 0, 0, 0);
            }
        __builtin_amdgcn_s_setprio(0);
    };

    int nsteps = (kend - kbeg) >> 5;
    if constexpr (SPLIT) {
        // 2-buffer, race-fixed: every vmcnt wait is BEFORE the barrier guarding its consumers.
        stage(0, kbeg);
        stage(1, kbeg + 32);
        asm volatile("s_waitcnt vmcnt(8)" ::: "memory");   // own buf0 landed (buf1 in flight)
        __builtin_amdgcn_s_barrier();                       // all waves' buf0 landed
        for (int t = 0; t < nsteps; ++t) {
            compute(t & 1);
            asm volatile("s_waitcnt lgkmcnt(0)" ::: "memory");   // my reads of buf t done
            if (t + 1 < nsteps)
                asm volatile("s_waitcnt vmcnt(0)" ::: "memory"); // my buf t+1 loads landed
            __builtin_amdgcn_s_barrier();                        // all waves: reads done + buf t+1 landed
            if (t + 2 < nsteps) stage(t & 1, kbeg + (t + 2) * 32);  // overwrite buf t for step t+2
        }
    } else {
        // depth-3 counted-vmcnt pipeline (r4/r10-proven); 4 gl_lds per stage per wave.
        stage(0, kbeg);
        stage(1, kbeg + 32);
        asm volatile("s_waitcnt vmcnt(4)" ::: "memory");   // buf0 landed (buf1 = 4 in flight)
        __builtin_amdgcn_s_barrier();
        int bufc = 0;
        for (int t = 0; t < nsteps; ++t) {
            int b2 = bufc + 2; if (b2 >= 3) b2 -= 3;
            if (t + 2 < nsteps) stage(b2, kbeg + (t + 2) * 32);   // overwrites buf(t-1): freed by prev barrier
            compute(bufc);
            if (t + 2 < nsteps) {
                asm volatile("s_waitcnt vmcnt(4) lgkmcnt(0)" ::: "memory");
            } else {
                asm volatile("s_waitcnt vmcnt(0) lgkmcnt(0)" ::: "memory");
            }
            __builtin_amdgcn_s_barrier();
            bufc = (bufc == 2) ? 0 : bufc + 1;
        }
    }

    if constexpr (MODE == 2) {
        // stage gelu(bf16) tile into SM[128][128] (col XOR-swizzled), then coalesced row stores
#pragma unroll
        for (int ni = 0; ni < 4; ni++) {
            int col = wn + ni * 16 + l15;
            float bb = bp[n0 + col];
#pragma unroll
            for (int mi = 0; mi < 4; mi++) {
#pragma unroll
                for (int r = 0; r < 4; r++) {
                    int row = wm + mi * 16 + quad * 4 + r;
                    float gv = gelu_fast(acc[mi][ni][r] + bb);
                    SM[row * 128 + (col ^ ((row & 7) << 3))] = f2bf(gv);
                }
            }
        }
        __syncthreads();
        int rr = tid >> 1, half = (tid & 1) * 64;
        int grow = m0 + rr;
        if (list[grow] >= 0) {
            u16* dst = (u16*)Cv + (size_t)grow * N + n0 + half;
            int xr = (rr & 7) << 3;
#pragma unroll
            for (int gch = 0; gch < 8; gch++) {
                int cb = (half + gch * 8) ^ xr;
                *(uint4*)(dst + gch * 8) = *(const uint4*)&SM[rr * 128 + cb];
            }
        }
        return;
    }

    float* Cf = (float*)Cv;
    if (MODE == 3 && zt != 0) Cf = (float*)Cv2;
#pragma unroll
    for (int ni = 0; ni < 4; ni++) {
        int col = n0 + wn + ni * 16 + l15;
        float bb = bp[col];
        if (MODE == 3 && zt != 0) bb = 0.f;   // bias added once (z=0 half)
#pragma unroll
        for (int mi = 0; mi < 4; mi++) {
#pragma unroll
            for (int r = 0; r < 4; r++) {
                int row = m0 + wm + mi * 16 + quad * 4 + r;
                float v2 = acc[mi][ni][r] + bb;
                if (MODE == 0) {
                    if (row < M) {
                        u16 hb = f2bf(v2);
                        ((u16*)Cv)[(size_t)row * N + col] = hb;
                        ((u16*)Cv2)[(size_t)row * N + col] = f2bf(v2 - bf2f(hb));
                    }
                } else if (MODE == 1) {
                    if (row < M) Cf[(size_t)row * N + col] = v2 + resid[(size_t)row * N + col];
                } else {
                    if (list[row] >= 0) Cf[(size_t)row * N + col] = v2;
                }
            }
        }
    }
}

// ---------------- MFMA attention: bf16 hi/lo qkv planes; block = (b, h, 64-q-tile), 4 waves ----------------
__global__ __launch_bounds__(256) void attn_mfma_kernel(const u16* __restrict__ qph,
        const u16* __restrict__ qpl, u16* __restrict__ ohi, u16* __restrict__ olo) {
    // bijective XCD swizzle over 768 blocks: XCD j gets 24 consecutive (b,h) with all 4 q-tiles
    int d = blockIdx.x + 4 * blockIdx.y;
    int j = d & 7, sdx = d >> 3;
    int v = j * 96 + sdx;
    int qbase = (v & 3) * 64;
    int by = v >> 2;
    int b = by / NH, h = by % NH;
    int tid = threadIdx.x;
    int w = tid >> 6, lane = tid & 63, l15 = lane & 15, quad = lane >> 4;

    __shared__ u16 Qh[64 * 64], Ql[64 * 64];
    __shared__ u16 Sh[64 * 64], Sl[64 * 64];   // K tile, then V^T tile
    __shared__ u16 Ph[64 * 72], Pl[64 * 72];

    int grow8 = lane >> 3;                     // row within 8-row gl_lds group
    int gsrc = ((lane & 7) ^ grow8) * 8;       // swizzled source granule (u16 offset)
    int srow = tid >> 2;                       // V^T: key index
    int scol = (tid & 3) * 16;                 // V^T: d base

    // --- stage Q (gl_lds, swizzled) ---
#pragma unroll
    for (int it = 0; it < 2; it++) {
        int r = qbase + w * 16 + it * 8 + grow8;
        int rc = min(r, SEQ - 1);
        size_t so = (size_t)(b * SEQ + rc) * 2304 + h * 64 + gsrc;
        gl_lds16(qph + so, &Qh[(w * 16 + it * 8) * 64]);
        gl_lds16(qpl + so, &Ql[(w * 16 + it * 8) * 64]);
    }
    __syncthreads();
    bf16x8 aqh[2], aql[2];
#pragma unroll
    for (int s2 = 0; s2 < 2; s2++) {
        int row = w * 16 + l15;
        int ad = row * 64 + (((s2 * 4 + quad) ^ (row & 7))) * 8;
        aqh[s2] = *(const bf16x8*)&Qh[ad];
        aql[s2] = *(const bf16x8*)&Ql[ad];
    }

    floatx4 sc[16];
#pragma unroll
    for (int f = 0; f < 16; f++) sc[f] = (floatx4){0.f, 0.f, 0.f, 0.f};

    for (int t = 0; t < 4; t++) {
#pragma unroll
        for (int it = 0; it < 2; it++) {
            int r = t * 64 + w * 16 + it * 8 + grow8;
            int rc = min(r, SEQ - 1);
            size_t so = (size_t)(b * SEQ + rc) * 2304 + 768 + h * 64 + gsrc;
            gl_lds16(qph + so, &Sh[(w * 16 + it * 8) * 64]);
            gl_lds16(qpl + so, &Sl[(w * 16 + it * 8) * 64]);
        }
        __syncthreads();
#pragma unroll
        for (int s = 0; s < 4; s++) {
            int row = s * 16 + l15;
#pragma unroll
            for (int s2 = 0; s2 < 2; s2++) {
                int ad = row * 64 + (((s2 * 4 + quad) ^ (row & 7))) * 8;
                bf16x8 bkh = *(const bf16x8*)&Sh[ad];
                bf16x8 bkl = *(const bf16x8*)&Sl[ad];
                sc[t * 4 + s] = __builtin_amdgcn_mfma_f32_16x16x32_bf16(aql[s2], bkh, sc[t * 4 + s], 0, 0, 0);
                sc[t * 4 + s] = __builtin_amdgcn_mfma_f32_16x16x32_bf16(aqh[s2], bkl, sc[t * 4 + s], 0, 0, 0);
                sc[t * 4 + s] = __builtin_amdgcn_mfma_f32_16x16x32_bf16(aqh[s2], bkh, sc[t * 4 + s], 0, 0, 0);
            }
        }
        __syncthreads();
    }

    float m[4] = {-1e30f, -1e30f, -1e30f, -1e30f};
#pragma unroll
    for (int f = 0; f < 16; f++) {
        int key = (f >> 2) * 64 + (f & 3) * 16 + l15;
        bool valid = key < SEQ;
#pragma unroll
        for (int r = 0; r < 4; r++) {
            float s = valid ? sc[f][r] * 0.125f : -1e30f;
            sc[f][r] = s;
            m[r] = fmaxf(m[r], s);
        }
    }
#pragma unroll
    for (int r = 0; r < 4; r++) {
#pragma unroll
        for (int off = 1; off < 16; off <<= 1) m[r] = fmaxf(m[r], __shfl_xor(m[r], off));
    }
    float sum[4] = {0.f, 0.f, 0.f, 0.f};
#pragma unroll
    for (int f = 0; f < 16; f++) {
#pragma unroll
        for (int r = 0; r < 4; r++) {
            float p = expf(sc[f][r] - m[r]);
            sc[f][r] = p;
            sum[r] += p;
        }
    }
    float inv[4];
#pragma unroll
    for (int r = 0; r < 4; r++) {
#pragma unroll
        for (int off = 1; off < 16; off <<= 1) sum[r] += __shfl_xor(sum[r], off);
        inv[r] = 1.f / sum[r];
    }

    floatx4 oacc[4];
#pragma unroll
    for (int sd = 0; sd < 4; sd++) oacc[sd] = (floatx4){0.f, 0.f, 0.f, 0.f};

    for (int t = 0; t < 4; t++) {
#pragma unroll
        for (int s = 0; s < 4; s++) {
#pragma unroll
            for (int r = 0; r < 4; r++) {
                float p = sc[t * 4 + s][r];
                u16 hb = f2bf(p);
                int row = w * 16 + quad * 4 + r;
                Ph[row * 72 + s * 16 + l15] = hb;
                Pl[row * 72 + s * 16 + l15] = f2bf(p - bf2f(hb));
            }
        }
        {
            // V^T staging from bf16 planes (u16-only), granule-swizzled for conflict-free reads
            int key = t * 64 + srow;
            int kc = min(key, SEQ - 1);   // garbage rows hit P==0 (masked scores), finite => safe
            size_t so = (size_t)(b * SEQ + kc) * 2304 + 1536 + h * 64 + scol;
            u16 hv[16], lv[16];
            *(uint4*)&hv[0] = *(const uint4*)(qph + so);
            *(uint4*)&hv[8] = *(const uint4*)(qph + so + 8);
            *(uint4*)&lv[0] = *(const uint4*)(qpl + so);
            *(uint4*)&lv[8] = *(const uint4*)(qpl + so + 8);
            int kg = srow >> 3, kw = srow & 7;
#pragma unroll
            for (int i = 0; i < 16; i++) {
                int dcol = scol + i;
                int idx2 = dcol * 64 + ((kg ^ (dcol & 7)) * 8) + kw;
                Sh[idx2] = hv[i];
                Sl[idx2] = lv[i];
            }
        }
        __syncthreads();
#pragma unroll
        for (int s2 = 0; s2 < 2; s2++) {
            bf16x8 aph = *(const bf16x8*)&Ph[(w * 16 + l15) * 72 + s2 * 32 + quad * 8];
            bf16x8 apl = *(const bf16x8*)&Pl[(w * 16 + l15) * 72 + s2 * 32 + quad * 8];
#pragma unroll
            for (int sd = 0; sd < 4; sd++) {
                int row = sd * 16 + l15;
                int ad = row * 64 + (((s2 * 4 + quad) ^ (row & 7))) * 8;
                bf16x8 bvh = *(const bf16x8*)&Sh[ad];
                bf16x8 bvl = *(const bf16x8*)&Sl[ad];
                oacc[sd] = __builtin_amdgcn_mfma_f32_16x16x32_bf16(apl, bvh, oacc[sd], 0, 0, 0);
                oacc[sd] = __builtin_amdgcn_mfma_f32_16x16x32_bf16(aph, bvl, oacc[sd], 0, 0, 0);
                oacc[sd] = __builtin_amdgcn_mfma_f32_16x16x32_bf16(aph, bvh, oacc[sd], 0, 0, 0);
            }
        }
        __syncthreads();
    }

#pragma unroll
    for (int sd = 0; sd < 4; sd++) {
#pragma unroll
        for (int r = 0; r < 4; r++) {
            int q = qbase + w * 16 + quad * 4 + r;
            if (q < SEQ) {
                float val = oacc[sd][r] * inv[r];
                u16 hb = f2bf(val);
                size_t o = ((size_t)(b * SEQ + q)) * 768 + h * 64 + sd * 16 + l15;
                ohi[o] = hb;
                olo[o] = f2bf(val - bf2f(hb));
            }
        }
    }
}

// ---------------- LN2 + gate (top-2 of 8): one WAVE per token, no LDS, no barriers, no atomics ----------------
__global__ __launch_bounds__(256) void ln2_gate_kernel(const float* __restrict__ x1,
        const float* __restrict__ g, const float* __restrict__ b, const float* __restrict__ wgT,
        u16* __restrict__ flat, int2* __restrict__ idx, float2* __restrict__ gate) {
    int w = threadIdx.x >> 6, lane = threadIdx.x & 63;
    int t = blockIdx.x * 4 + w;
    if (t >= T_TOK) return;
    const float* xp = x1 + (size_t)t * 768;
    float v[3][4];
    float s = 0.f, q = 0.f;
#pragma unroll
    for (int i = 0; i < 3; i++) {
        float4 f4 = *(const float4*)(xp + i * 256 + lane * 4);
        v[i][0] = f4.x; v[i][1] = f4.y; v[i][2] = f4.z; v[i][3] = f4.w;
#pragma unroll
        for (int j2 = 0; j2 < 4; j2++) { s += v[i][j2]; q += v[i][j2] * v[i][j2]; }
    }
    s = wred_sum(s); q = wred_sum(q);
    float mean = s * (1.f / 768.f);
    float var = q * (1.f / 768.f) - mean * mean;
    float rs = rsqrtf(var + 1e-5f);
    float fs[3][4];
#pragma unroll
    for (int i = 0; i < 3; i++) {
        int d0 = i * 256 + lane * 4;
        float4 g4 = *(const float4*)(g + d0);
        float4 b4 = *(const float4*)(b + d0);
        float gg[4] = {g4.x, g4.y, g4.z, g4.w};
        float bb[4] = {b4.x, b4.y, b4.z, b4.w};
        u16 hv[4];
#pragma unroll
        for (int j2 = 0; j2 < 4; j2++) {
            float f = (v[i][j2] - mean) * rs * gg[j2] + bb[j2];
            fs[i][j2] = f;
            hv[j2] = f2bf(f);
        }
        *(uint2*)&flat[(size_t)t * 768 + d0] = *(const uint2*)hv;
    }
    float lg[8];
#pragma unroll
    for (int e = 0; e < 8; e++) {
        float p = 0.f;
#pragma unroll
        for (int i = 0; i < 3; i++) {
            float4 wv = *(const float4*)(wgT + e * 768 + i * 256 + lane * 4);
            p = fmaf(fs[i][0], wv.x, p);
            p = fmaf(fs[i][1], wv.y, p);
            p = fmaf(fs[i][2], wv.z, p);
            p = fmaf(fs[i][3], wv.w, p);
        }
        lg[e] = wred_sum(p);
    }
    if (lane == 0) {
        float b0 = -1e30f, b1 = -1e30f;
        int i0 = 0, i1 = 0;
#pragma unroll
        for (int e = 0; e < 8; e++) {     // strict > keeps first occurrence (jax tie-break)
            float le = lg[e];
            if (le > b0) { b1 = b0; i1 = i0; b0 = le; i0 = e; }
            else if (le > b1) { b1 = le; i1 = e; }
        }
        float ex = expf(b1 - b0);
        float den = 1.f + ex;
        idx[t] = make_int2(i0, i1);
        gate[t] = make_float2(1.f / den, ex / den);
    }
}

// ---------------- routing: 1-block atomic-free histogram + offsets + deterministic scatter ----------------
__global__ __launch_bounds__(256) void route_kernel(const int2* __restrict__ idx,
        int* __restrict__ asg, int* __restrict__ list, int* __restrict__ pos) {
    int tid = threadIdx.x, w = tid >> 6, lane = tid & 63;
    __shared__ int wcnt[4][8];
    __shared__ int run[8];

    // phase 1: histogram via register counts + wave reduce (no atomics)
    int myc[8] = {0, 0, 0, 0, 0, 0, 0, 0};
    for (int t = tid; t < T_TOK; t += 256) {
        int2 id = idx[t];
#pragma unroll
        for (int e = 0; e < 8; e++) myc[e] += (id.x == e) + (id.y == e);
    }
#pragma unroll
    for (int e = 0; e < 8; e++) {
        int c = wred_sum_i(myc[e]);
        if (lane == 0) wcnt[w][e] = c;
    }
    __syncthreads();
    if (tid == 0) {
        int acc = 0;
        for (int e = 0; e < 8; e++) {
            run[e] = acc;
            asg[e] = acc;
            int c = wcnt[0][e] + wcnt[1][e] + wcnt[2][e] + wcnt[3][e];
            acc += (c + 127) & ~127;
        }
        asg[8] = acc;
    }
    __syncthreads();

    // phase 2: deterministic scatter via ballot prefix ranks (entry order: token, then x before y)
    unsigned long long lt = (1ull << lane) - 1ull;   // lanes below me (lane<64, no UB for 63)
    for (int c0 = 0; c0 < T_TOK; c0 += 256) {
        int t = c0 + tid;
        bool valid = t < T_TOK;
        int ex = valid ? idx[t].x : -1;
        int ey = valid ? idx[t].y : -1;
        int rkx = 0, rky = 0;
        int wtot[8];
#pragma unroll
        for (int e = 0; e < 8; e++) {
            unsigned long long mx = __ballot(ex == e);
            unsigned long long my = __ballot(ey == e);
            int r = __popcll(mx & lt) + __popcll(my & lt);
            if (ex == e) rkx = r;
            if (ey == e) rky = r;       // own x-entry targets ex != ey, contributes 0
            wtot[e] = __popcll(mx) + __popcll(my);
        }
        if (lane == 0) {
#pragma unroll
            for (int e = 0; e < 8; e++) wcnt[w][e] = wtot[e];
        }
        __syncthreads();
        if (valid) {
            int wpx = 0, wpy = 0;
            for (int w2 = 0; w2 < w; w2++) { wpx += wcnt[w2][ex]; wpy += wcnt[w2][ey]; }
            int p0 = run[ex] + wpx + rkx;
            int p1 = run[ey] + wpy + rky;
            list[p0] = t * 2;
            pos[t * 2] = p0;
            list[p1] = t * 2 + 1;
            pos[t * 2 + 1] = p1;
        }
        __syncthreads();
        if (tid < 8) run[tid] += wcnt[0][tid] + wcnt[1][tid] + wcnt[2][tid] + wcnt[3][tid];
        __syncthreads();
    }
}

// ---------------- final: out = x1 + g0*(y0[p0]+y1[p0]) + g1*(y0[p1]+y1[p1])  (f32 out) ----------------
__global__ __launch_bounds__(256) void final_kernel(const float* __restrict__ x1,
        const float* __restrict__ yp0, const float* __restrict__ yp1, const int* __restrict__ pos,
        const float2* __restrict__ gate, float* __restrict__ out) {
    int t = blockIdx.x, tid = threadIdx.x;
    float2 g = gate[t];
    int p0 = pos[t * 2], p1 = pos[t * 2 + 1];
#pragma unroll
    for (int i = 0; i < 3; i++) {
        int d = tid + i * 256;
        float y0 = yp0[(size_t)p0 * 768 + d] + yp1[(size_t)p0 * 768 + d];
        float y1 = yp0[(size_t)p1 * 768 + d] + yp1[(size_t)p1 * 768 + d];
        out[(size_t)t * 768 + d] = x1[(size_t)t * 768 + d] + g.x * y0 + g.y * y1;
    }
}

extern "C" void kernel_launch(void* const* d_in, const int* in_sizes, int n_in,
                              void* d_out, int out_size, void* d_ws, size_t ws_size,
                              hipStream_t stream) {
    const float* x      = (const float*)d_in[0];
    const float* ln1_g  = (const float*)d_in[1];
    const float* ln1_b  = (const float*)d_in[2];
    const float* qkv_w  = (const float*)d_in[3];
    const float* qkv_b  = (const float*)d_in[4];
    const float* proj_w = (const float*)d_in[5];
    const float* proj_b = (const float*)d_in[6];
    const float* ln2_g  = (const float*)d_in[7];
    const float* ln2_b  = (const float*)d_in[8];
    const float* w_gate = (const float*)d_in[9];
    const float* w1     = (const float*)d_in[10];
    const float* b1     = (const float*)d_in[11];
    const float* w2     = (const float*)d_in[12];
    const float* b2     = (const float*)d_in[13];

    char* ws = (char*)d_ws;
    size_t off = 0;
    auto alloc = [&](size_t bytes) { size_t cur = off; off = (off + bytes + 255) & ~(size_t)255; return cur; };
    // region0: h_hi|h_lo|qkv_hi|qkv_lo|o_hi|o_lo (dead before MoE2) — reused as ypair0 (22.8MB <= 48.4MB)
    u16*    h_hi   = (u16*)   (ws + alloc((size_t)T_TOK * 768 * 2));
    u16*    h_lo   = (u16*)   (ws + alloc((size_t)T_TOK * 768 * 2));
    u16*    qkv_hi = (u16*)   (ws + alloc((size_t)T_TOK * 2304 * 2));
    u16*    qkv_lo = (u16*)   (ws + alloc((size_t)T_TOK * 2304 * 2));
    u16*    o_hi   = (u16*)   (ws + alloc((size_t)T_TOK * 768 * 2));
    u16*    o_lo   = (u16*)   (ws + alloc((size_t)T_TOK * 768 * 2));
    float*  ypair0 = (float*) ws;   // 7424*768*4 = 22.8MB <= region0
    float*  x1     = (float*) (ws + alloc((size_t)T_TOK * 768 * 4));
    u16*    flat   = (u16*)   (ws + alloc((size_t)T_TOK * 768 * 2));
    int2*   idx    = (int2*)  (ws + alloc((size_t)T_TOK * 8));
    float2* gate   = (float2*)(ws + alloc((size_t)T_TOK * 8));
    float*  wgT    = (float*) (ws + alloc((size_t)8 * 768 * 4));
    int*    asg    = (int*)   (ws + alloc(64));     // aligned_start[9]
    int*    list   = (int*)   (ws + alloc((size_t)LISTN * 4));
    int*    pos    = (int*)   (ws + alloc((size_t)T_TOK * 2 * 4));
    u16*    hid    = (u16*)   (ws + alloc((size_t)LISTN * 3072 * 2));
    u16*    qkvt_h = (u16*)   (ws + alloc((size_t)2304 * 768 * 2));
    u16*    qkvt_l = (u16*)   (ws + alloc((size_t)2304 * 768 * 2));
    u16*    projt_h = (u16*)  (ws + alloc((size_t)768 * 768 * 2));
    u16*    projt_l = (u16*)  (ws + alloc((size_t)768 * 768 * 2));
    u16*    w1t    = (u16*)   (ws + alloc((size_t)8 * 3072 * 768 * 2));
    u16*    w2t    = (u16*)   (ws + alloc((size_t)8 * 768 * 3072 * 2));
    float*  ypair1 = (float*) w1t;  // w1t (37.7MB) dead after moe1; ypair1 needs 22.8MB

    hipMemsetAsync(list, 0xFF, (size_t)LISTN * 4, stream);

    // fused weight prep (4 transposes + gate transpose in one dispatch)
    prep_kernel<<<PREP_TOTAL, 256, 0, stream>>>(qkv_w, qkvt_h, qkvt_l, proj_w, projt_h, projt_l,
                                                w1, w1t, w2, w2t, w_gate, wgT);

    ln1_kernel<<<T_TOK, 256, 0, stream>>>(x, ln1_g, ln1_b, h_hi, h_lo);
    gemm128<0><<<dim3(25, 18), 256, 0, stream>>>(h_hi, h_lo, qkvt_h, qkvt_l, qkv_b, qkv_hi,
                                                 qkv_lo, nullptr, nullptr, nullptr, T_TOK, 2304, 768);
    attn_mfma_kernel<<<dim3(4, 192), 256, 0, stream>>>(qkv_hi, qkv_lo, o_hi, o_lo);
    gemm128<1><<<dim3(25, 6), 256, 0, stream>>>(o_hi, o_lo, projt_h, projt_l, proj_b, x1,
                                                nullptr, x, nullptr, nullptr, T_TOK, 768, 768);
    ln2_gate_kernel<<<T_TOK / 4, 256, 0, stream>>>(x1, ln2_g, ln2_b, wgT, flat, idx, gate);
    route_kernel<<<1, 256, 0, stream>>>(idx, asg, list, pos);
    gemm128<2><<<dim3(MOE_MT, 24), 256, 0, stream>>>(flat, nullptr, w1t, nullptr, b1, hid,
                                                     nullptr, nullptr, list, asg, LISTN, 3072, 768);
    gemm128<3><<<dim3(MOE_MT, 6, 2), 256, 0, stream>>>(hid, nullptr, w2t, nullptr, b2, ypair0,
                                                       ypair1, nullptr, list, asg, LISTN, 768, 3072);
    final_kernel<<<T_TOK, 256, 0, stream>>>(x1, ypair0, ypair1, pos, gate, (float*)d_out);
}